// Round 3
// baseline (4254.792 us; speedup 1.0000x reference)
//
#include <hip/hip_runtime.h>
#include <math.h>

// TransformerPolicy forward — bf16 MFMA GEMMs + MFMA flash attention.
// B=32, T=196, E=768, NH=12, dh=64, NB=8, FF=3072, FLAT=150528, TF=512, NA=4
// R1: fused LN-stats in GEMM epilogues (W1/W2 write bf16 + row sum/sumsq),
//     ln2 applied in-place on bf16, ln3+next-ln_in fused into one per-row kernel.
// R2/R3: identical resubmission (GPU-acquisition timeouts; no counters to
//     justify a new diff — one unverified change at a time).

#define B_    32
#define T_    196
#define E_    768
#define NH_   12
#define DH_   64
#define FF_   3072
#define NB_   8
#define FLAT_ 150528
#define TF2_  1024
#define TF_   512
#define QKV_LD 2304   // packed q|k|v output row stride

typedef __attribute__((ext_vector_type(8))) short short8;
typedef __attribute__((ext_vector_type(4))) float float4v;

static __device__ __forceinline__ unsigned short f2bf(float f) {
  unsigned int u = __float_as_uint(f);
  u = u + 0x7fffu + ((u >> 16) & 1u);   // round-to-nearest-even
  return (unsigned short)(u >> 16);
}

static __device__ __forceinline__ float bf2f(unsigned short u) {
  return __uint_as_float((unsigned int)u << 16);
}

// ---------------------------------------------------------------- patches (bf16 out)
__global__ __launch_bounds__(256) void gather_patches(const float* __restrict__ fov,
                                                      unsigned short* __restrict__ P) {
  int idx = blockIdx.x * 256 + threadIdx.x;
  const int total = B_ * T_ * E_;
  if (idx >= total) return;
  int m = idx / E_;
  int k = idx % E_;
  int b = m / T_, t = m % T_;
  int ph = t / 14, pw = t % 14;
  int c = k >> 8;
  int kh = (k >> 4) & 15;
  int kw = k & 15;
  P[idx] = f2bf(fov[((b * 3 + c) * 224 + ph * 16 + kh) * 224 + pw * 16 + kw]);
}

// elementwise fp32 -> bf16
__global__ __launch_bounds__(256) void cvt_bf16(const float* __restrict__ in,
                                                unsigned short* __restrict__ outp, int n) {
  int idx = blockIdx.x * 256 + threadIdx.x;
  if (idx < n) outp[idx] = f2bf(in[idx]);
}

// transpose + convert: in [R][C] fp32 (possibly NB matrices), out [C][R] bf16
__global__ __launch_bounds__(256) void transpose_cvt(const float* __restrict__ in,
                                                     unsigned short* __restrict__ outp,
                                                     int R, int Cc,
                                                     long in_ms, long out_ms) {
  __shared__ float tile[32][33];
  const float* ip = in + (size_t)blockIdx.z * in_ms;
  unsigned short* op = outp + (size_t)blockIdx.z * out_ms;
  int c0 = blockIdx.x * 32, r0 = blockIdx.y * 32;
  int tx = threadIdx.x & 31, ty = threadIdx.x >> 5;  // ty 0..7
#pragma unroll
  for (int i = 0; i < 32; i += 8)
    tile[ty + i][tx] = ip[(size_t)(r0 + ty + i) * Cc + c0 + tx];
  __syncthreads();
#pragma unroll
  for (int i = 0; i < 32; i += 8)
    op[(size_t)(c0 + ty + i) * R + r0 + tx] = f2bf(tile[tx][ty + i]);
}

// ---------------------------------------------------------------- MFMA GEMM
// C[M,N] = A[M,K](bf16) @ Bt[N,K](bf16)^T + bias. 128x128 tile, BK=32, 256 thr.
// Optional: stats != nullptr -> atomically accumulate per-row (sum, sumsq) of the
// fp32 (pre-bf16-rounding) outputs into stats[2*row], stats[2*row+1].
template <typename OutT>
__global__ __launch_bounds__(256) void gemm_bt_mfma(const unsigned short* __restrict__ A,
                                                    const unsigned short* __restrict__ Bt,
                                                    const float* __restrict__ bias,
                                                    OutT* __restrict__ C,
                                                    int M, int N, int K,
                                                    float* __restrict__ stats) {
  __shared__ unsigned short As[128 * 32];  // [row][k] row-major, 64B rows
  __shared__ unsigned short Bs[128 * 32];
  const int tid = threadIdx.x;
  const int wave = tid >> 6, lane = tid & 63;
  const int wr = wave >> 1, wc = wave & 1;
  const int m0 = blockIdx.y * 128, n0 = blockIdx.x * 128;

  float4v acc[4][4];
#pragma unroll
  for (int i = 0; i < 4; ++i)
#pragma unroll
    for (int j = 0; j < 4; ++j) acc[i][j] = (float4v){0.f, 0.f, 0.f, 0.f};

  const int sA = wave * 128 + lane;
  const int arow = sA >> 2;
  const int acol = (sA & 3) * 8;
  const unsigned short* Abase = A + (size_t)(m0 + arow) * K + acol;
  const unsigned short* Bbase = Bt + (size_t)(n0 + arow) * K + acol;
  unsigned short* lA = As + wave * 1024;
  unsigned short* lB = Bs + wave * 1024;

  const int kg = (lane >> 4) * 8;
  const int rsel = lane & 15;

  for (int k0 = 0; k0 < K; k0 += 32) {
    __syncthreads();
    __builtin_amdgcn_global_load_lds(
        (const __attribute__((address_space(1))) unsigned int*)(const void*)(Abase + k0),
        (__attribute__((address_space(3))) unsigned int*)(void*)(lA), 16, 0, 0);
    __builtin_amdgcn_global_load_lds(
        (const __attribute__((address_space(1))) unsigned int*)(const void*)(Abase + (size_t)16 * K + k0),
        (__attribute__((address_space(3))) unsigned int*)(void*)(lA + 512), 16, 0, 0);
    __builtin_amdgcn_global_load_lds(
        (const __attribute__((address_space(1))) unsigned int*)(const void*)(Bbase + k0),
        (__attribute__((address_space(3))) unsigned int*)(void*)(lB), 16, 0, 0);
    __builtin_amdgcn_global_load_lds(
        (const __attribute__((address_space(1))) unsigned int*)(const void*)(Bbase + (size_t)16 * K + k0),
        (__attribute__((address_space(3))) unsigned int*)(void*)(lB + 512), 16, 0, 0);
    asm volatile("s_waitcnt vmcnt(0)" ::: "memory");
    __syncthreads();

    short8 af[4], bf[4];
#pragma unroll
    for (int mi = 0; mi < 4; ++mi)
      af[mi] = *(const short8*)(As + (size_t)(wr * 64 + mi * 16 + rsel) * 32 + kg);
#pragma unroll
    for (int ni = 0; ni < 4; ++ni)
      bf[ni] = *(const short8*)(Bs + (size_t)(wc * 64 + ni * 16 + rsel) * 32 + kg);
#pragma unroll
    for (int mi = 0; mi < 4; ++mi)
#pragma unroll
      for (int ni = 0; ni < 4; ++ni)
        acc[mi][ni] = __builtin_amdgcn_mfma_f32_16x16x32_bf16(af[mi], bf[ni], acc[mi][ni], 0, 0, 0);
  }

  // C/D layout: col = lane&15, row = (lane>>4)*4 + r
  const int cr0 = m0 + wr * 64 + (lane >> 4) * 4;
  const int cc0 = n0 + wc * 64 + (lane & 15);
  float bv[4];
#pragma unroll
  for (int ni = 0; ni < 4; ++ni) bv[ni] = bias ? bias[cc0 + ni * 16] : 0.f;
#pragma unroll
  for (int mi = 0; mi < 4; ++mi) {
#pragma unroll
    for (int r = 0; r < 4; ++r) {
      int row = cr0 + mi * 16 + r;
      float s = 0.f, s2 = 0.f;
#pragma unroll
      for (int ni = 0; ni < 4; ++ni) {
        float v = acc[mi][ni][r] + bv[ni];
        if constexpr (sizeof(OutT) == 2)
          C[(size_t)row * N + cc0 + ni * 16] = f2bf(v);
        else
          C[(size_t)row * N + cc0 + ni * 16] = v;
        s += v; s2 += v * v;
      }
      if (stats) {
        // reduce over the 16 lanes (rsel) sharing this row; quad stays intact
#pragma unroll
        for (int o = 1; o < 16; o <<= 1) {
          s += __shfl_xor(s, o);
          s2 += __shfl_xor(s2, o);
        }
        if ((lane & 15) == 0) {
          atomicAdd(&stats[2 * row], s);
          atomicAdd(&stats[2 * row + 1], s2);
        }
      }
    }
  }
}

// ---------------------------------------------------------------- LayerNorm (reg-cached)
// zstats: optional stats buffer to zero for the *next* stats-accumulating GEMM.
template <int CNT>
__global__ __launch_bounds__(256) void ln_kernel(const float* __restrict__ in,
                                                 const float* __restrict__ g,
                                                 const float* __restrict__ bta,
                                                 const float* __restrict__ add_src,
                                                 float* __restrict__ out32,
                                                 unsigned short* __restrict__ out16,
                                                 int relu,
                                                 float* __restrict__ zstats) {
  const int R = CNT * 256;
  int row = blockIdx.x;
  if (zstats && threadIdx.x == 0) { zstats[2 * row] = 0.f; zstats[2 * row + 1] = 0.f; }
  const float* xr = in + (size_t)row * R;
  float v[CNT];
  float s = 0.f, s2 = 0.f;
#pragma unroll
  for (int i = 0; i < CNT; ++i) {
    float t = xr[i * 256 + threadIdx.x];
    v[i] = t; s += t; s2 += t * t;
  }
#pragma unroll
  for (int o = 32; o > 0; o >>= 1) { s += __shfl_down(s, o); s2 += __shfl_down(s2, o); }
  __shared__ float rs_[4], rs2_[4];
  int wave = threadIdx.x >> 6, lane = threadIdx.x & 63;
  if (lane == 0) { rs_[wave] = s; rs2_[wave] = s2; }
  __syncthreads();
  s = rs_[0] + rs_[1] + rs_[2] + rs_[3];
  s2 = rs2_[0] + rs2_[1] + rs2_[2] + rs2_[3];
  float mean = s / (float)R;
  float inv = rsqrtf(s2 / (float)R - mean * mean + 1e-5f);
#pragma unroll
  for (int i = 0; i < CNT; ++i) {
    int c = i * 256 + threadIdx.x;
    float t = (v[i] - mean) * inv * g[c] + bta[c];
    if (relu) t = fmaxf(t, 0.f);
    if (add_src) t += add_src[(size_t)row * R + c];
    if (out32) out32[(size_t)row * R + c] = t;
    else out16[(size_t)row * R + c] = f2bf(t);
  }
}

// LN2+ReLU applied in-place on bf16 W1 output using precomputed row stats.
// Also zeroes stats2 for the following W2 GEMM.
__global__ __launch_bounds__(256) void ln2_fused(unsigned short* __restrict__ hb,
                                                 const float* __restrict__ stats,
                                                 const float* __restrict__ g,
                                                 const float* __restrict__ bta,
                                                 float* __restrict__ zstats) {
  int row = blockIdx.x;
  if (threadIdx.x == 0) { zstats[2 * row] = 0.f; zstats[2 * row + 1] = 0.f; }
  float s = stats[2 * row], s2 = stats[2 * row + 1];
  const float R = (float)FF_;
  float mean = s / R;
  float inv = rsqrtf(s2 / R - mean * mean + 1e-5f);
  unsigned short* hr = hb + (size_t)row * FF_;
#pragma unroll
  for (int i = 0; i < 6; ++i) {
    int c = (i * 256 + threadIdx.x) * 2;
    unsigned int u = *(const unsigned int*)(hr + c);
    float2 gv = *(const float2*)(g + c);
    float2 bv = *(const float2*)(bta + c);
    float v0 = __uint_as_float((u & 0xffffu) << 16);
    float v1 = __uint_as_float(u & 0xffff0000u);
    float t0 = fmaxf((v0 - mean) * inv * gv.x + bv.x, 0.f);
    float t1 = fmaxf((v1 - mean) * inv * gv.y + bv.y, 0.f);
    *(unsigned int*)(hr + c) = (unsigned int)f2bf(t0) | ((unsigned int)f2bf(t1) << 16);
  }
}

// x += LN3(h2) using precomputed stats; then (optionally) compute next block's
// ln_in over the updated row (full row is live in registers) -> xn bf16.
__global__ __launch_bounds__(256) void ln3_fuse(const unsigned short* __restrict__ h2,
                                                const float* __restrict__ stats,
                                                const float* __restrict__ g3,
                                                const float* __restrict__ b3,
                                                float* __restrict__ x,
                                                const float* __restrict__ gin,
                                                const float* __restrict__ bin,
                                                unsigned short* __restrict__ xn) {
  int row = blockIdx.x;
  float s = stats[2 * row], s2 = stats[2 * row + 1];
  const float R = (float)E_;
  float mean = s / R;
  float inv = rsqrtf(s2 / R - mean * mean + 1e-5f);
  const unsigned short* hr = h2 + (size_t)row * E_;
  float* xr = x + (size_t)row * E_;
  float y[3];
  float ys = 0.f, ys2 = 0.f;
#pragma unroll
  for (int i = 0; i < 3; ++i) {
    int c = i * 256 + threadIdx.x;
    float hv = bf2f(hr[c]);
    float t = (hv - mean) * inv * g3[c] + b3[c];
    float yy = xr[c] + t;
    xr[c] = yy;
    y[i] = yy; ys += yy; ys2 += yy * yy;
  }
  if (!gin) return;  // last block: no following ln_in
#pragma unroll
  for (int o = 32; o > 0; o >>= 1) { ys += __shfl_down(ys, o); ys2 += __shfl_down(ys2, o); }
  __shared__ float rs_[4], rs2_[4];
  int wave = threadIdx.x >> 6, lane = threadIdx.x & 63;
  if (lane == 0) { rs_[wave] = ys; rs2_[wave] = ys2; }
  __syncthreads();
  ys = rs_[0] + rs_[1] + rs_[2] + rs_[3];
  ys2 = rs2_[0] + rs2_[1] + rs2_[2] + rs2_[3];
  float m2 = ys / R;
  float inv2 = rsqrtf(ys2 / R - m2 * m2 + 1e-5f);
#pragma unroll
  for (int i = 0; i < 3; ++i) {
    int c = i * 256 + threadIdx.x;
    xn[(size_t)row * E_ + c] = f2bf((y[i] - m2) * inv2 * gin[c] + bin[c]);
  }
}

// LN over FLAT per sample (32 rows)
__global__ __launch_bounds__(1024) void ln_big(const float* __restrict__ in,
                                               const float* __restrict__ g,
                                               const float* __restrict__ bta,
                                               float* __restrict__ outp) {
  __shared__ float red[16], red2[16];
  int row = blockIdx.x;
  const float* xr = in + (size_t)row * FLAT_;
  float s = 0.f, s2 = 0.f;
  for (int i = threadIdx.x; i < FLAT_; i += 1024) { float t = xr[i]; s += t; s2 += t * t; }
  for (int o = 32; o > 0; o >>= 1) { s += __shfl_down(s, o); s2 += __shfl_down(s2, o); }
  int wave = threadIdx.x >> 6, lane = threadIdx.x & 63;
  if (lane == 0) { red[wave] = s; red2[wave] = s2; }
  __syncthreads();
  if (threadIdx.x == 0) {
    float a = 0.f, b2 = 0.f;
    for (int i = 0; i < 16; ++i) { a += red[i]; b2 += red2[i]; }
    red[0] = a; red2[0] = b2;
  }
  __syncthreads();
  s = red[0]; s2 = red2[0];
  float mean = s / (float)FLAT_;
  float inv = rsqrtf(s2 / (float)FLAT_ - mean * mean + 1e-5f);
  for (int i = threadIdx.x; i < FLAT_; i += 1024)
    outp[(size_t)row * FLAT_ + i] = (xr[i] - mean) * inv * g[i] + bta[i];
}

// ---------------------------------------------------------------- attention (MFMA flash)
// qkv bf16 [B*T][2304]: q@0, k@+768, v@+1536. x[b,t,h*64+d] += softmax(qk^T/14) v.
__global__ __launch_bounds__(256) void attention_mfma(const unsigned short* __restrict__ qkv,
                                                      float* __restrict__ x) {
  __shared__ unsigned short smem[28672];     // 57,344 B
  unsigned short* Kh = smem;                 // [2 half][224 s][32 k]
  unsigned short* Vt = smem + 14336;         // [7 chunk][64 d][32 s]
  unsigned short* Ps = smem;                 // [4 wave][7 chunk][16 m][32 k] (aliases Kh)
  const int chunk = blockIdx.x, h = blockIdx.y, b = blockIdx.z;
  const int tid = threadIdx.x, wave = tid >> 6, lane = tid & 63;
  const int quad = lane >> 4, rsel = lane & 15;

  // ---- stage K (row-major halves) and V (transposed [d][s]) ----
  for (int task = tid; task < 1792; task += 256) {
    int s = task >> 3, seg = task & 7;       // seg: 8-col group
    short8 kv = {0, 0, 0, 0, 0, 0, 0, 0};
    short8 vv = {0, 0, 0, 0, 0, 0, 0, 0};
    if (s < 196) {
      const unsigned short* gp = qkv + (size_t)(b * 196 + s) * 2304 + h * 64 + seg * 8;
      kv = *(const short8*)(gp + 768);
      vv = *(const short8*)(gp + 1536);
    }
    *(short8*)(Kh + (seg >> 2) * 7168 + s * 32 + (seg & 3) * 8) = kv;
    int c = s >> 5, sw = s & 31;
#pragma unroll
    for (int j = 0; j < 8; ++j)
      Vt[c * 2048 + (seg * 8 + j) * 32 + sw] = (unsigned short)vv[j];
  }

  // Q A-frags direct from global (A[m=lane&15][k=quad*8+j]); clamp padded rows
  int qrow = chunk * 64 + wave * 16 + rsel;
  int qc = qrow < 196 ? qrow : 195;
  const unsigned short* qp = qkv + (size_t)(b * 196 + qc) * 2304 + h * 64 + quad * 8;
  short8 a0 = *(const short8*)qp;
  short8 a1 = *(const short8*)(qp + 32);

  __syncthreads();

  // ---- S = Q K^T ----
  float4v S[14];
#pragma unroll
  for (int ni = 0; ni < 14; ++ni) S[ni] = (float4v){0.f, 0.f, 0.f, 0.f};
#pragma unroll
  for (int ni = 0; ni < 14; ++ni) {
    const unsigned short* kb = Kh + (ni * 16 + rsel) * 32 + quad * 8;
    S[ni] = __builtin_amdgcn_mfma_f32_16x16x32_bf16(a0, *(const short8*)kb, S[ni], 0, 0, 0);
    S[ni] = __builtin_amdgcn_mfma_f32_16x16x32_bf16(a1, *(const short8*)(kb + 7168), S[ni], 0, 0, 0);
  }

  // ---- softmax (exact, per row t = quad*4 + r) ----
  const float scale = 1.0f / 14.0f;
  float mr[4] = {-1e30f, -1e30f, -1e30f, -1e30f};
#pragma unroll
  for (int ni = 0; ni < 14; ++ni) {
    int col = ni * 16 + rsel;
#pragma unroll
    for (int r = 0; r < 4; ++r) {
      float v = (col < 196) ? S[ni][r] * scale : -1e30f;
      S[ni][r] = v;
      mr[r] = fmaxf(mr[r], v);
    }
  }
#pragma unroll
  for (int o = 1; o < 16; o <<= 1) {
#pragma unroll
    for (int r = 0; r < 4; ++r) mr[r] = fmaxf(mr[r], __shfl_xor(mr[r], o));
  }
  float lr[4] = {0.f, 0.f, 0.f, 0.f};
#pragma unroll
  for (int ni = 0; ni < 14; ++ni) {
#pragma unroll
    for (int r = 0; r < 4; ++r) {
      float p = __expf(S[ni][r] - mr[r]);
      S[ni][r] = p;
      lr[r] += p;
    }
  }
#pragma unroll
  for (int o = 1; o < 16; o <<= 1) {
#pragma unroll
    for (int r = 0; r < 4; ++r) lr[r] += __shfl_xor(lr[r], o);
  }

  // ---- P (C-layout) -> LDS -> A-layout ----
  __syncthreads();  // all waves done reading Kh
#pragma unroll
  for (int ni = 0; ni < 14; ++ni) {
    int c = ni >> 1, cw = (ni & 1) * 16 + rsel;
#pragma unroll
    for (int r = 0; r < 4; ++r)
      Ps[wave * 3584 + c * 512 + (quad * 4 + r) * 32 + cw] = f2bf(S[ni][r]);
  }
  __syncthreads();

  // ---- O = P V ----
  float4v O[4];
#pragma unroll
  for (int nd = 0; nd < 4; ++nd) O[nd] = (float4v){0.f, 0.f, 0.f, 0.f};
#pragma unroll
  for (int c = 0; c < 7; ++c) {
    short8 pa = *(const short8*)(Ps + wave * 3584 + c * 512 + rsel * 32 + quad * 8);
#pragma unroll
    for (int nd = 0; nd < 4; ++nd) {
      short8 vb = *(const short8*)(Vt + c * 2048 + (nd * 16 + rsel) * 32 + quad * 8);
      O[nd] = __builtin_amdgcn_mfma_f32_16x16x32_bf16(pa, vb, O[nd], 0, 0, 0);
    }
  }

  // ---- x += O / l (disjoint (t,h) slices: race-free) ----
  int t0 = chunk * 64 + wave * 16 + quad * 4;
  float invl[4];
#pragma unroll
  for (int r = 0; r < 4; ++r) invl[r] = 1.0f / lr[r];
#pragma unroll
  for (int r = 0; r < 4; ++r) {
    int t = t0 + r;
    if (t < 196) {
      float* xp = x + (size_t)(b * 196 + t) * 768 + h * 64 + rsel;
#pragma unroll
      for (int nd = 0; nd < 4; ++nd) xp[nd * 16] += O[nd][r] * invl[r];
    }
  }
}

// ---------------------------------------------------------------- trunk1
__global__ __launch_bounds__(256) void init_bias_kernel(const float* __restrict__ bias,
                                                        float* __restrict__ outp,
                                                        int M, int N) {
  int idx = blockIdx.x * 256 + threadIdx.x;
  if (idx < M * N) outp[idx] = bias[idx % N];
}

#define TKS_ 512
__global__ __launch_bounds__(256) void trunk1_kernel(const float* __restrict__ f,
                                                     const float* __restrict__ W,
                                                     float* __restrict__ t1) {
  __shared__ float fs[32][33];
  const int tid = threadIdx.x;
  const int nt = tid & 63;
  const int mg = tid >> 6;
  const int n = blockIdx.x * 256 + nt * 4;
  const int k0 = blockIdx.y * TKS_;
  float4 acc[8];
#pragma unroll
  for (int r = 0; r < 8; ++r) acc[r] = make_float4(0.f, 0.f, 0.f, 0.f);
  const int lm = tid >> 3;
  const int lk = (tid & 7) * 4;
  for (int kc = 0; kc < TKS_; kc += 32) {
    __syncthreads();
    *(float4*)&fs[lm][lk] = *(const float4*)&f[(size_t)lm * FLAT_ + k0 + kc + lk];
    __syncthreads();
#pragma unroll 8
    for (int k2 = 0; k2 < 32; ++k2) {
      float4 w4 = *(const float4*)&W[(size_t)(k0 + kc + k2) * TF2_ + n];
#pragma unroll
      for (int r = 0; r < 8; ++r) {
        float fv = fs[mg * 8 + r][k2];
        acc[r].x += fv * w4.x; acc[r].y += fv * w4.y;
        acc[r].z += fv * w4.z; acc[r].w += fv * w4.w;
      }
    }
  }
#pragma unroll
  for (int r = 0; r < 8; ++r) {
    atomicAdd(&t1[(mg * 8 + r) * TF2_ + n + 0], acc[r].x);
    atomicAdd(&t1[(mg * 8 + r) * TF2_ + n + 1], acc[r].y);
    atomicAdd(&t1[(mg * 8 + r) * TF2_ + n + 2], acc[r].z);
    atomicAdd(&t1[(mg * 8 + r) * TF2_ + n + 3], acc[r].w);
  }
}

// ---------------------------------------------------------------- small gemms / head
__global__ __launch_bounds__(256) void small_gemm(const float* __restrict__ A,
                                                  const float* __restrict__ W,
                                                  const float* __restrict__ bias,
                                                  float* __restrict__ C,
                                                  int N, int K) {
  int m = blockIdx.y;
  int n = blockIdx.x * 256 + threadIdx.x;
  if (n >= N) return;
  float acc = bias[n];
  const float* ar = A + (size_t)m * K;
  for (int k = 0; k < K; ++k) acc += ar[k] * W[(size_t)k * N + n];
  C[(size_t)m * N + n] = acc;
}

__global__ __launch_bounds__(256) void cat_kernel(const float* __restrict__ cur,
                                                  const float* __restrict__ tgt,
                                                  const float* __restrict__ f,
                                                  float* __restrict__ outp) {
  int idx = blockIdx.x * 256 + threadIdx.x;
  const int total = B_ * 516;
  if (idx >= total) return;
  int m = idx / 516, j = idx % 516;
  float v;
  if (j < 2) v = cur[m * 2 + j];
  else if (j < 4) v = tgt[m * 2 + j - 2];
  else v = f[m * 512 + j - 4];
  outp[idx] = v;
}

__global__ __launch_bounds__(64) void head2_kernel(const float* __restrict__ h1,
                                                   const float* __restrict__ W,
                                                   const float* __restrict__ bias,
                                                   float* __restrict__ outp) {
  int m = blockIdx.x;
  int n = threadIdx.x;
  if (n < 4) {
    float acc = bias[n];
    for (int kk = 0; kk < TF_; ++kk) acc += h1[m * TF_ + kk] * W[kk * 4 + n];
    outp[m * 4 + n] = acc;
  }
}

// ---------------------------------------------------------------- launch
extern "C" void kernel_launch(void* const* d_in, const int* in_sizes, int n_in,
                              void* d_out, int out_size, void* d_ws, size_t ws_size,
                              hipStream_t stream) {
  const float* fov    = (const float*)d_in[0];
  const float* cur    = (const float*)d_in[1];
  const float* tgt    = (const float*)d_in[2];
  const float* conv_w = (const float*)d_in[3];
  const float* conv_b = (const float*)d_in[4];
  const float* ln_in_g = (const float*)d_in[5];
  const float* ln_in_b = (const float*)d_in[6];
  const float* blk_q  = (const float*)d_in[7];
  const float* blk_k  = (const float*)d_in[8];
  const float* blk_v  = (const float*)d_in[9];
  const float* ln1_g  = (const float*)d_in[10];
  const float* ln1_b  = (const float*)d_in[11];
  const float* w1     = (const float*)d_in[12];
  const float* b1     = (const float*)d_in[13];
  const float* ln2_g  = (const float*)d_in[14];
  const float* ln2_b  = (const float*)d_in[15];
  const float* w2     = (const float*)d_in[16];
  const float* b2     = (const float*)d_in[17];
  const float* ln3_g  = (const float*)d_in[18];
  const float* ln3_b  = (const float*)d_in[19];
  const float* img_g  = (const float*)d_in[20];
  const float* img_b  = (const float*)d_in[21];
  const float* t1w    = (const float*)d_in[22];
  const float* t1b    = (const float*)d_in[23];
  const float* tln1_g = (const float*)d_in[24];
  const float* tln1_b = (const float*)d_in[25];
  const float* t2w    = (const float*)d_in[26];
  const float* t2b    = (const float*)d_in[27];
  const float* tln2_g = (const float*)d_in[28];
  const float* tln2_b = (const float*)d_in[29];
  const float* h1w    = (const float*)d_in[30];
  const float* h1b    = (const float*)d_in[31];
  const float* hln_g  = (const float*)d_in[32];
  const float* hln_b  = (const float*)d_in[33];
  const float* h2w    = (const float*)d_in[34];
  const float* h2b    = (const float*)d_in[35];
  float* out = (float*)d_out;

  float* ws = (float*)d_ws;
  size_t off = 0;
  const size_t XE = (size_t)B_ * T_ * E_;      // 4,816,896
  const size_t XF = (size_t)B_ * T_ * FF_;     // 19,267,584
  float* x    = ws + off; off += XE;                   // residual (fp32)
  float* tmp  = ws + off; off += XE;                   // f (ln_big out)
  unsigned short* xn_b = (unsigned short*)(ws + off); off += XE / 2;   // LN out bf16 / patches
  unsigned short* hb_b = (unsigned short*)(ws + off); off += XF / 2;   // W1 out / ln2 bf16 (in-place)
  unsigned short* tmp_b = (unsigned short*)(ws + off); off += XE / 2;  // W2 out bf16
  unsigned short* qkv_bf = (unsigned short*)(ws + off); off += (size_t)B_ * T_ * QKV_LD / 2;
  unsigned short* cwb  = (unsigned short*)(ws + off); off += (size_t)E_ * E_ / 2;
  unsigned short* wqkvb = (unsigned short*)(ws + off); off += (size_t)NB_ * QKV_LD * E_ / 2;
  unsigned short* w1b  = (unsigned short*)(ws + off); off += (size_t)NB_ * E_ * FF_ / 2;
  unsigned short* w2b  = (unsigned short*)(ws + off); off += (size_t)NB_ * E_ * FF_ / 2;
  float* stats1 = ws + off; off += (size_t)B_ * T_ * 2;   // W1 row sums
  float* stats2 = ws + off; off += (size_t)B_ * T_ * 2;   // W2 row sums
  float* t1 = ws + off; off += B_ * TF2_;
  float* t2 = ws + off; off += B_ * TF_;
  float* cb = ws + off; off += B_ * 516;
  float* h1 = ws + off; off += B_ * TF_;
  (void)ws_size; (void)in_sizes; (void)n_in; (void)out_size;

  const int M = B_ * T_;  // 6272
  dim3 blk(256);

  // ---- weight conversion (bf16, transposed to [N][K]) ----
  cvt_bf16<<<(E_ * E_ + 255) / 256, blk, 0, stream>>>(conv_w, cwb, E_ * E_);
  transpose_cvt<<<dim3(24, 24, NB_), blk, 0, stream>>>(blk_q, wqkvb + 0 * E_ * E_,
                                                       E_, E_, (long)E_ * E_, (long)QKV_LD * E_);
  transpose_cvt<<<dim3(24, 24, NB_), blk, 0, stream>>>(blk_k, wqkvb + 1 * E_ * E_,
                                                       E_, E_, (long)E_ * E_, (long)QKV_LD * E_);
  transpose_cvt<<<dim3(24, 24, NB_), blk, 0, stream>>>(blk_v, wqkvb + 2 * E_ * E_,
                                                       E_, E_, (long)E_ * E_, (long)QKV_LD * E_);
  transpose_cvt<<<dim3(96, 24, NB_), blk, 0, stream>>>(w1, w1b, E_, FF_,
                                                       (long)E_ * FF_, (long)E_ * FF_);
  transpose_cvt<<<dim3(24, 96, NB_), blk, 0, stream>>>(w2, w2b, FF_, E_,
                                                       (long)E_ * FF_, (long)E_ * FF_);

  // ---- patch embed ----
  gather_patches<<<(B_ * T_ * E_ + 255) / 256, blk, 0, stream>>>(fov, xn_b);
  gemm_bt_mfma<float><<<dim3(E_ / 128, M / 128), blk, 0, stream>>>(xn_b, cwb, conv_b, x,
                                                                   M, E_, E_, nullptr);

  // ---- block 0 ln_in (later blocks get it fused into ln3_fuse) ----
  ln_kernel<3><<<M, blk, 0, stream>>>(x, ln_in_g, ln_in_b,
                                      nullptr, nullptr, xn_b, 0, nullptr);

  // ---- transformer blocks ----
  for (int i = 0; i < NB_; ++i) {
    gemm_bt_mfma<unsigned short><<<dim3(QKV_LD / 128, M / 128), blk, 0, stream>>>(
        xn_b, wqkvb + (size_t)i * QKV_LD * E_, nullptr, qkv_bf, M, QKV_LD, E_, nullptr);
    attention_mfma<<<dim3(4, NH_, B_), blk, 0, stream>>>(qkv_bf, x);
    ln_kernel<3><<<M, blk, 0, stream>>>(x, ln1_g + i * E_, ln1_b + i * E_,
                                        nullptr, nullptr, xn_b, 0, stats1);
    gemm_bt_mfma<unsigned short><<<dim3(FF_ / 128, M / 128), blk, 0, stream>>>(
        xn_b, w1b + (size_t)i * E_ * FF_, b1 + i * FF_, hb_b, M, FF_, E_, stats1);
    ln2_fused<<<M, blk, 0, stream>>>(hb_b, stats1, ln2_g + i * FF_, ln2_b + i * FF_, stats2);
    gemm_bt_mfma<unsigned short><<<dim3(E_ / 128, M / 128), blk, 0, stream>>>(
        hb_b, w2b + (size_t)i * E_ * FF_, b2 + i * E_, tmp_b, M, E_, FF_, stats2);
    const float* gin = (i < NB_ - 1) ? ln_in_g + (i + 1) * E_ : nullptr;
    const float* bin = (i < NB_ - 1) ? ln_in_b + (i + 1) * E_ : nullptr;
    ln3_fuse<<<M, blk, 0, stream>>>(tmp_b, stats2, ln3_g + i * E_, ln3_b + i * E_,
                                    x, gin, bin, xn_b);
  }

  // ---- head ----
  float* f = tmp;
  ln_big<<<B_, dim3(1024), 0, stream>>>(x, img_g, img_b, f);
  init_bias_kernel<<<(B_ * TF2_ + 255) / 256, blk, 0, stream>>>(t1b, t1, B_, TF2_);
  trunk1_kernel<<<dim3(TF2_ / 256, FLAT_ / TKS_), blk, 0, stream>>>(f, t1w, t1);
  ln_kernel<4><<<B_, blk, 0, stream>>>(t1, tln1_g, tln1_b, nullptr, t1, nullptr, 1, nullptr);
  small_gemm<<<dim3(2, B_), blk, 0, stream>>>(t1, t2w, t2b, t2, TF_, TF2_);
  ln_kernel<2><<<B_, blk, 0, stream>>>(t2, tln2_g, tln2_b, nullptr, t2, nullptr, 1, nullptr);
  cat_kernel<<<(B_ * 516 + 255) / 256, blk, 0, stream>>>(cur, tgt, t2, cb);
  small_gemm<<<dim3(2, B_), blk, 0, stream>>>(cb, h1w, h1b, h1, TF_, 516);
  ln_kernel<2><<<B_, blk, 0, stream>>>(h1, hln_g, hln_b, nullptr, h1, nullptr, 1, nullptr);
  head2_kernel<<<B_, dim3(64), 0, stream>>>(h1, h2w, h2b, out);
}

// Round 4
// 4012.111 us; speedup vs baseline: 1.0605x; 1.0605x over previous
//
#include <hip/hip_runtime.h>
#include <math.h>

// TransformerPolicy forward — bf16 MFMA GEMMs + MFMA flash attention.
// B=32, T=196, E=768, NH=12, dh=64, NB=8, FF=3072, FLAT=150528, TF=512, NA=4
// R1 (verified, 4255 µs): fused LN-stats in GEMM epilogues, ln2 in-place bf16,
//     ln3+next-ln_in fused.
// R4: trunk1 rework — counters showed 420 µs @ 17% VALU / 15% HBM / 64 VGPR:
//     (a) atomicAdd (9.6M ops, 294-way contention, 154 MB writeback) -> per-k-block
//         partials + split-K reduce kernel;
//     (b) launch_bounds(256,2) + explicit 8-deep float4 W-load batches so the
//         register allocator keeps 8 loads in flight (was ~2 at VGPR=64).

#define B_    32
#define T_    196
#define E_    768
#define NH_   12
#define DH_   64
#define FF_   3072
#define NB_   8
#define FLAT_ 150528
#define TF2_  1024
#define TF_   512
#define QKV_LD 2304   // packed q|k|v output row stride

typedef __attribute__((ext_vector_type(8))) short short8;
typedef __attribute__((ext_vector_type(4))) float float4v;

static __device__ __forceinline__ unsigned short f2bf(float f) {
  unsigned int u = __float_as_uint(f);
  u = u + 0x7fffu + ((u >> 16) & 1u);   // round-to-nearest-even
  return (unsigned short)(u >> 16);
}

static __device__ __forceinline__ float bf2f(unsigned short u) {
  return __uint_as_float((unsigned int)u << 16);
}

// ---------------------------------------------------------------- patches (bf16 out)
__global__ __launch_bounds__(256) void gather_patches(const float* __restrict__ fov,
                                                      unsigned short* __restrict__ P) {
  int idx = blockIdx.x * 256 + threadIdx.x;
  const int total = B_ * T_ * E_;
  if (idx >= total) return;
  int m = idx / E_;
  int k = idx % E_;
  int b = m / T_, t = m % T_;
  int ph = t / 14, pw = t % 14;
  int c = k >> 8;
  int kh = (k >> 4) & 15;
  int kw = k & 15;
  P[idx] = f2bf(fov[((b * 3 + c) * 224 + ph * 16 + kh) * 224 + pw * 16 + kw]);
}

// elementwise fp32 -> bf16
__global__ __launch_bounds__(256) void cvt_bf16(const float* __restrict__ in,
                                                unsigned short* __restrict__ outp, int n) {
  int idx = blockIdx.x * 256 + threadIdx.x;
  if (idx < n) outp[idx] = f2bf(in[idx]);
}

// transpose + convert: in [R][C] fp32 (possibly NB matrices), out [C][R] bf16
__global__ __launch_bounds__(256) void transpose_cvt(const float* __restrict__ in,
                                                     unsigned short* __restrict__ outp,
                                                     int R, int Cc,
                                                     long in_ms, long out_ms) {
  __shared__ float tile[32][33];
  const float* ip = in + (size_t)blockIdx.z * in_ms;
  unsigned short* op = outp + (size_t)blockIdx.z * out_ms;
  int c0 = blockIdx.x * 32, r0 = blockIdx.y * 32;
  int tx = threadIdx.x & 31, ty = threadIdx.x >> 5;  // ty 0..7
#pragma unroll
  for (int i = 0; i < 32; i += 8)
    tile[ty + i][tx] = ip[(size_t)(r0 + ty + i) * Cc + c0 + tx];
  __syncthreads();
#pragma unroll
  for (int i = 0; i < 32; i += 8)
    op[(size_t)(c0 + ty + i) * R + r0 + tx] = f2bf(tile[tx][ty + i]);
}

// ---------------------------------------------------------------- MFMA GEMM
// C[M,N] = A[M,K](bf16) @ Bt[N,K](bf16)^T + bias. 128x128 tile, BK=32, 256 thr.
// Optional: stats != nullptr -> atomically accumulate per-row (sum, sumsq) of the
// fp32 (pre-bf16-rounding) outputs into stats[2*row], stats[2*row+1].
template <typename OutT>
__global__ __launch_bounds__(256) void gemm_bt_mfma(const unsigned short* __restrict__ A,
                                                    const unsigned short* __restrict__ Bt,
                                                    const float* __restrict__ bias,
                                                    OutT* __restrict__ C,
                                                    int M, int N, int K,
                                                    float* __restrict__ stats) {
  __shared__ unsigned short As[128 * 32];  // [row][k] row-major, 64B rows
  __shared__ unsigned short Bs[128 * 32];
  const int tid = threadIdx.x;
  const int wave = tid >> 6, lane = tid & 63;
  const int wr = wave >> 1, wc = wave & 1;
  const int m0 = blockIdx.y * 128, n0 = blockIdx.x * 128;

  float4v acc[4][4];
#pragma unroll
  for (int i = 0; i < 4; ++i)
#pragma unroll
    for (int j = 0; j < 4; ++j) acc[i][j] = (float4v){0.f, 0.f, 0.f, 0.f};

  const int sA = wave * 128 + lane;
  const int arow = sA >> 2;
  const int acol = (sA & 3) * 8;
  const unsigned short* Abase = A + (size_t)(m0 + arow) * K + acol;
  const unsigned short* Bbase = Bt + (size_t)(n0 + arow) * K + acol;
  unsigned short* lA = As + wave * 1024;
  unsigned short* lB = Bs + wave * 1024;

  const int kg = (lane >> 4) * 8;
  const int rsel = lane & 15;

  for (int k0 = 0; k0 < K; k0 += 32) {
    __syncthreads();
    __builtin_amdgcn_global_load_lds(
        (const __attribute__((address_space(1))) unsigned int*)(const void*)(Abase + k0),
        (__attribute__((address_space(3))) unsigned int*)(void*)(lA), 16, 0, 0);
    __builtin_amdgcn_global_load_lds(
        (const __attribute__((address_space(1))) unsigned int*)(const void*)(Abase + (size_t)16 * K + k0),
        (__attribute__((address_space(3))) unsigned int*)(void*)(lA + 512), 16, 0, 0);
    __builtin_amdgcn_global_load_lds(
        (const __attribute__((address_space(1))) unsigned int*)(const void*)(Bbase + k0),
        (__attribute__((address_space(3))) unsigned int*)(void*)(lB), 16, 0, 0);
    __builtin_amdgcn_global_load_lds(
        (const __attribute__((address_space(1))) unsigned int*)(const void*)(Bbase + (size_t)16 * K + k0),
        (__attribute__((address_space(3))) unsigned int*)(void*)(lB + 512), 16, 0, 0);
    asm volatile("s_waitcnt vmcnt(0)" ::: "memory");
    __syncthreads();

    short8 af[4], bf[4];
#pragma unroll
    for (int mi = 0; mi < 4; ++mi)
      af[mi] = *(const short8*)(As + (size_t)(wr * 64 + mi * 16 + rsel) * 32 + kg);
#pragma unroll
    for (int ni = 0; ni < 4; ++ni)
      bf[ni] = *(const short8*)(Bs + (size_t)(wc * 64 + ni * 16 + rsel) * 32 + kg);
#pragma unroll
    for (int mi = 0; mi < 4; ++mi)
#pragma unroll
      for (int ni = 0; ni < 4; ++ni)
        acc[mi][ni] = __builtin_amdgcn_mfma_f32_16x16x32_bf16(af[mi], bf[ni], acc[mi][ni], 0, 0, 0);
  }

  // C/D layout: col = lane&15, row = (lane>>4)*4 + r
  const int cr0 = m0 + wr * 64 + (lane >> 4) * 4;
  const int cc0 = n0 + wc * 64 + (lane & 15);
  float bv[4];
#pragma unroll
  for (int ni = 0; ni < 4; ++ni) bv[ni] = bias ? bias[cc0 + ni * 16] : 0.f;
#pragma unroll
  for (int mi = 0; mi < 4; ++mi) {
#pragma unroll
    for (int r = 0; r < 4; ++r) {
      int row = cr0 + mi * 16 + r;
      float s = 0.f, s2 = 0.f;
#pragma unroll
      for (int ni = 0; ni < 4; ++ni) {
        float v = acc[mi][ni][r] + bv[ni];
        if constexpr (sizeof(OutT) == 2)
          C[(size_t)row * N + cc0 + ni * 16] = f2bf(v);
        else
          C[(size_t)row * N + cc0 + ni * 16] = v;
        s += v; s2 += v * v;
      }
      if (stats) {
        // reduce over the 16 lanes (rsel) sharing this row; quad stays intact
#pragma unroll
        for (int o = 1; o < 16; o <<= 1) {
          s += __shfl_xor(s, o);
          s2 += __shfl_xor(s2, o);
        }
        if ((lane & 15) == 0) {
          atomicAdd(&stats[2 * row], s);
          atomicAdd(&stats[2 * row + 1], s2);
        }
      }
    }
  }
}

// ---------------------------------------------------------------- LayerNorm (reg-cached)
// zstats: optional stats buffer to zero for the *next* stats-accumulating GEMM.
template <int CNT>
__global__ __launch_bounds__(256) void ln_kernel(const float* __restrict__ in,
                                                 const float* __restrict__ g,
                                                 const float* __restrict__ bta,
                                                 const float* __restrict__ add_src,
                                                 float* __restrict__ out32,
                                                 unsigned short* __restrict__ out16,
                                                 int relu,
                                                 float* __restrict__ zstats) {
  const int R = CNT * 256;
  int row = blockIdx.x;
  if (zstats && threadIdx.x == 0) { zstats[2 * row] = 0.f; zstats[2 * row + 1] = 0.f; }
  const float* xr = in + (size_t)row * R;
  float v[CNT];
  float s = 0.f, s2 = 0.f;
#pragma unroll
  for (int i = 0; i < CNT; ++i) {
    float t = xr[i * 256 + threadIdx.x];
    v[i] = t; s += t; s2 += t * t;
  }
#pragma unroll
  for (int o = 32; o > 0; o >>= 1) { s += __shfl_down(s, o); s2 += __shfl_down(s2, o); }
  __shared__ float rs_[4], rs2_[4];
  int wave = threadIdx.x >> 6, lane = threadIdx.x & 63;
  if (lane == 0) { rs_[wave] = s; rs2_[wave] = s2; }
  __syncthreads();
  s = rs_[0] + rs_[1] + rs_[2] + rs_[3];
  s2 = rs2_[0] + rs2_[1] + rs2_[2] + rs2_[3];
  float mean = s / (float)R;
  float inv = rsqrtf(s2 / (float)R - mean * mean + 1e-5f);
#pragma unroll
  for (int i = 0; i < CNT; ++i) {
    int c = i * 256 + threadIdx.x;
    float t = (v[i] - mean) * inv * g[c] + bta[c];
    if (relu) t = fmaxf(t, 0.f);
    if (add_src) t += add_src[(size_t)row * R + c];
    if (out32) out32[(size_t)row * R + c] = t;
    else out16[(size_t)row * R + c] = f2bf(t);
  }
}

// LN2+ReLU applied in-place on bf16 W1 output using precomputed row stats.
// Also zeroes stats2 for the following W2 GEMM.
__global__ __launch_bounds__(256) void ln2_fused(unsigned short* __restrict__ hb,
                                                 const float* __restrict__ stats,
                                                 const float* __restrict__ g,
                                                 const float* __restrict__ bta,
                                                 float* __restrict__ zstats) {
  int row = blockIdx.x;
  if (threadIdx.x == 0) { zstats[2 * row] = 0.f; zstats[2 * row + 1] = 0.f; }
  float s = stats[2 * row], s2 = stats[2 * row + 1];
  const float R = (float)FF_;
  float mean = s / R;
  float inv = rsqrtf(s2 / R - mean * mean + 1e-5f);
  unsigned short* hr = hb + (size_t)row * FF_;
#pragma unroll
  for (int i = 0; i < 6; ++i) {
    int c = (i * 256 + threadIdx.x) * 2;
    unsigned int u = *(const unsigned int*)(hr + c);
    float2 gv = *(const float2*)(g + c);
    float2 bv = *(const float2*)(bta + c);
    float v0 = __uint_as_float((u & 0xffffu) << 16);
    float v1 = __uint_as_float(u & 0xffff0000u);
    float t0 = fmaxf((v0 - mean) * inv * gv.x + bv.x, 0.f);
    float t1 = fmaxf((v1 - mean) * inv * gv.y + bv.y, 0.f);
    *(unsigned int*)(hr + c) = (unsigned int)f2bf(t0) | ((unsigned int)f2bf(t1) << 16);
  }
}

// x += LN3(h2) using precomputed stats; then (optionally) compute next block's
// ln_in over the updated row (full row is live in registers) -> xn bf16.
__global__ __launch_bounds__(256) void ln3_fuse(const unsigned short* __restrict__ h2,
                                                const float* __restrict__ stats,
                                                const float* __restrict__ g3,
                                                const float* __restrict__ b3,
                                                float* __restrict__ x,
                                                const float* __restrict__ gin,
                                                const float* __restrict__ bin,
                                                unsigned short* __restrict__ xn) {
  int row = blockIdx.x;
  float s = stats[2 * row], s2 = stats[2 * row + 1];
  const float R = (float)E_;
  float mean = s / R;
  float inv = rsqrtf(s2 / R - mean * mean + 1e-5f);
  const unsigned short* hr = h2 + (size_t)row * E_;
  float* xr = x + (size_t)row * E_;
  float y[3];
  float ys = 0.f, ys2 = 0.f;
#pragma unroll
  for (int i = 0; i < 3; ++i) {
    int c = i * 256 + threadIdx.x;
    float hv = bf2f(hr[c]);
    float t = (hv - mean) * inv * g3[c] + b3[c];
    float yy = xr[c] + t;
    xr[c] = yy;
    y[i] = yy; ys += yy; ys2 += yy * yy;
  }
  if (!gin) return;  // last block: no following ln_in
#pragma unroll
  for (int o = 32; o > 0; o >>= 1) { ys += __shfl_down(ys, o); ys2 += __shfl_down(ys2, o); }
  __shared__ float rs_[4], rs2_[4];
  int wave = threadIdx.x >> 6, lane = threadIdx.x & 63;
  if (lane == 0) { rs_[wave] = ys; rs2_[wave] = ys2; }
  __syncthreads();
  ys = rs_[0] + rs_[1] + rs_[2] + rs_[3];
  ys2 = rs2_[0] + rs2_[1] + rs2_[2] + rs2_[3];
  float m2 = ys / R;
  float inv2 = rsqrtf(ys2 / R - m2 * m2 + 1e-5f);
#pragma unroll
  for (int i = 0; i < 3; ++i) {
    int c = i * 256 + threadIdx.x;
    xn[(size_t)row * E_ + c] = f2bf((y[i] - m2) * inv2 * gin[c] + bin[c]);
  }
}

// LN over FLAT per sample (32 rows)
__global__ __launch_bounds__(1024) void ln_big(const float* __restrict__ in,
                                               const float* __restrict__ g,
                                               const float* __restrict__ bta,
                                               float* __restrict__ outp) {
  __shared__ float red[16], red2[16];
  int row = blockIdx.x;
  const float* xr = in + (size_t)row * FLAT_;
  float s = 0.f, s2 = 0.f;
  for (int i = threadIdx.x; i < FLAT_; i += 1024) { float t = xr[i]; s += t; s2 += t * t; }
  for (int o = 32; o > 0; o >>= 1) { s += __shfl_down(s, o); s2 += __shfl_down(s2, o); }
  int wave = threadIdx.x >> 6, lane = threadIdx.x & 63;
  if (lane == 0) { red[wave] = s; red2[wave] = s2; }
  __syncthreads();
  if (threadIdx.x == 0) {
    float a = 0.f, b2 = 0.f;
    for (int i = 0; i < 16; ++i) { a += red[i]; b2 += red2[i]; }
    red[0] = a; red2[0] = b2;
  }
  __syncthreads();
  s = red[0]; s2 = red2[0];
  float mean = s / (float)FLAT_;
  float inv = rsqrtf(s2 / (float)FLAT_ - mean * mean + 1e-5f);
  for (int i = threadIdx.x; i < FLAT_; i += 1024)
    outp[(size_t)row * FLAT_ + i] = (xr[i] - mean) * inv * g[i] + bta[i];
}

// ---------------------------------------------------------------- attention (MFMA flash)
// qkv bf16 [B*T][2304]: q@0, k@+768, v@+1536. x[b,t,h*64+d] += softmax(qk^T/14) v.
__global__ __launch_bounds__(256) void attention_mfma(const unsigned short* __restrict__ qkv,
                                                      float* __restrict__ x) {
  __shared__ unsigned short smem[28672];     // 57,344 B
  unsigned short* Kh = smem;                 // [2 half][224 s][32 k]
  unsigned short* Vt = smem + 14336;         // [7 chunk][64 d][32 s]
  unsigned short* Ps = smem;                 // [4 wave][7 chunk][16 m][32 k] (aliases Kh)
  const int chunk = blockIdx.x, h = blockIdx.y, b = blockIdx.z;
  const int tid = threadIdx.x, wave = tid >> 6, lane = tid & 63;
  const int quad = lane >> 4, rsel = lane & 15;

  // ---- stage K (row-major halves) and V (transposed [d][s]) ----
  for (int task = tid; task < 1792; task += 256) {
    int s = task >> 3, seg = task & 7;       // seg: 8-col group
    short8 kv = {0, 0, 0, 0, 0, 0, 0, 0};
    short8 vv = {0, 0, 0, 0, 0, 0, 0, 0};
    if (s < 196) {
      const unsigned short* gp = qkv + (size_t)(b * 196 + s) * 2304 + h * 64 + seg * 8;
      kv = *(const short8*)(gp + 768);
      vv = *(const short8*)(gp + 1536);
    }
    *(short8*)(Kh + (seg >> 2) * 7168 + s * 32 + (seg & 3) * 8) = kv;
    int c = s >> 5, sw = s & 31;
#pragma unroll
    for (int j = 0; j < 8; ++j)
      Vt[c * 2048 + (seg * 8 + j) * 32 + sw] = (unsigned short)vv[j];
  }

  // Q A-frags direct from global (A[m=lane&15][k=quad*8+j]); clamp padded rows
  int qrow = chunk * 64 + wave * 16 + rsel;
  int qc = qrow < 196 ? qrow : 195;
  const unsigned short* qp = qkv + (size_t)(b * 196 + qc) * 2304 + h * 64 + quad * 8;
  short8 a0 = *(const short8*)qp;
  short8 a1 = *(const short8*)(qp + 32);

  __syncthreads();

  // ---- S = Q K^T ----
  float4v S[14];
#pragma unroll
  for (int ni = 0; ni < 14; ++ni) S[ni] = (float4v){0.f, 0.f, 0.f, 0.f};
#pragma unroll
  for (int ni = 0; ni < 14; ++ni) {
    const unsigned short* kb = Kh + (ni * 16 + rsel) * 32 + quad * 8;
    S[ni] = __builtin_amdgcn_mfma_f32_16x16x32_bf16(a0, *(const short8*)kb, S[ni], 0, 0, 0);
    S[ni] = __builtin_amdgcn_mfma_f32_16x16x32_bf16(a1, *(const short8*)(kb + 7168), S[ni], 0, 0, 0);
  }

  // ---- softmax (exact, per row t = quad*4 + r) ----
  const float scale = 1.0f / 14.0f;
  float mr[4] = {-1e30f, -1e30f, -1e30f, -1e30f};
#pragma unroll
  for (int ni = 0; ni < 14; ++ni) {
    int col = ni * 16 + rsel;
#pragma unroll
    for (int r = 0; r < 4; ++r) {
      float v = (col < 196) ? S[ni][r] * scale : -1e30f;
      S[ni][r] = v;
      mr[r] = fmaxf(mr[r], v);
    }
  }
#pragma unroll
  for (int o = 1; o < 16; o <<= 1) {
#pragma unroll
    for (int r = 0; r < 4; ++r) mr[r] = fmaxf(mr[r], __shfl_xor(mr[r], o));
  }
  float lr[4] = {0.f, 0.f, 0.f, 0.f};
#pragma unroll
  for (int ni = 0; ni < 14; ++ni) {
#pragma unroll
    for (int r = 0; r < 4; ++r) {
      float p = __expf(S[ni][r] - mr[r]);
      S[ni][r] = p;
      lr[r] += p;
    }
  }
#pragma unroll
  for (int o = 1; o < 16; o <<= 1) {
#pragma unroll
    for (int r = 0; r < 4; ++r) lr[r] += __shfl_xor(lr[r], o);
  }

  // ---- P (C-layout) -> LDS -> A-layout ----
  __syncthreads();  // all waves done reading Kh
#pragma unroll
  for (int ni = 0; ni < 14; ++ni) {
    int c = ni >> 1, cw = (ni & 1) * 16 + rsel;
#pragma unroll
    for (int r = 0; r < 4; ++r)
      Ps[wave * 3584 + c * 512 + (quad * 4 + r) * 32 + cw] = f2bf(S[ni][r]);
  }
  __syncthreads();

  // ---- O = P V ----
  float4v O[4];
#pragma unroll
  for (int nd = 0; nd < 4; ++nd) O[nd] = (float4v){0.f, 0.f, 0.f, 0.f};
#pragma unroll
  for (int c = 0; c < 7; ++c) {
    short8 pa = *(const short8*)(Ps + wave * 3584 + c * 512 + rsel * 32 + quad * 8);
#pragma unroll
    for (int nd = 0; nd < 4; ++nd) {
      short8 vb = *(const short8*)(Vt + c * 2048 + (nd * 16 + rsel) * 32 + quad * 8);
      O[nd] = __builtin_amdgcn_mfma_f32_16x16x32_bf16(pa, vb, O[nd], 0, 0, 0);
    }
  }

  // ---- x += O / l (disjoint (t,h) slices: race-free) ----
  int t0 = chunk * 64 + wave * 16 + quad * 4;
  float invl[4];
#pragma unroll
  for (int r = 0; r < 4; ++r) invl[r] = 1.0f / lr[r];
#pragma unroll
  for (int r = 0; r < 4; ++r) {
    int t = t0 + r;
    if (t < 196) {
      float* xp = x + (size_t)(b * 196 + t) * 768 + h * 64 + rsel;
#pragma unroll
      for (int nd = 0; nd < 4; ++nd) xp[nd * 16] += O[nd][r] * invl[r];
    }
  }
}

// ---------------------------------------------------------------- trunk1
__global__ __launch_bounds__(256) void init_bias_kernel(const float* __restrict__ bias,
                                                        float* __restrict__ outp,
                                                        int M, int N) {
  int idx = blockIdx.x * 256 + threadIdx.x;
  if (idx < M * N) outp[idx] = bias[idx % N];
}

#define TKS_ 512
#define KB_  (FLAT_ / TKS_)   // 294 k-blocks

// stage 1: partial[kb][32][TF2] = f[32][k-slice] @ W[k-slice][TF2]. No atomics.
__global__ __launch_bounds__(256, 2) void trunk1_kernel(const float* __restrict__ f,
                                                        const float* __restrict__ W,
                                                        float* __restrict__ partial) {
  __shared__ float fs[32][33];
  const int tid = threadIdx.x;
  const int nt = tid & 63;
  const int mg = tid >> 6;
  const int n = blockIdx.x * 256 + nt * 4;
  const int k0 = blockIdx.y * TKS_;
  float4 acc[8];
#pragma unroll
  for (int r = 0; r < 8; ++r) acc[r] = make_float4(0.f, 0.f, 0.f, 0.f);
  const int lm = tid >> 3;
  const int lk = (tid & 7) * 4;
  for (int kc = 0; kc < TKS_; kc += 32) {
    __syncthreads();
    *(float4*)&fs[lm][lk] = *(const float4*)&f[(size_t)lm * FLAT_ + k0 + kc + lk];
    __syncthreads();
#pragma unroll
    for (int kb8 = 0; kb8 < 32; kb8 += 8) {
      // batch-issue 8 independent float4 W loads (needs the 256-VGPR budget)
      float4 w[8];
#pragma unroll
      for (int j = 0; j < 8; ++j)
        w[j] = *(const float4*)&W[(size_t)(k0 + kc + kb8 + j) * TF2_ + n];
#pragma unroll
      for (int j = 0; j < 8; ++j) {
#pragma unroll
        for (int r = 0; r < 8; ++r) {
          float fv = fs[mg * 8 + r][kb8 + j];
          acc[r].x += fv * w[j].x; acc[r].y += fv * w[j].y;
          acc[r].z += fv * w[j].z; acc[r].w += fv * w[j].w;
        }
      }
    }
  }
  const size_t base = ((size_t)blockIdx.y * 32 + mg * 8) * TF2_ + n;
#pragma unroll
  for (int r = 0; r < 8; ++r)
    *(float4*)&partial[base + (size_t)r * TF2_] = acc[r];
}

// stage 2: t1 (bias-initialized) += sum_kb partial[kb]. grid (32, 8) split-K.
__global__ __launch_bounds__(256) void trunk1_reduce(const float* __restrict__ partial,
                                                     float* __restrict__ t1) {
  int out4 = blockIdx.x * 1024 + threadIdx.x * 4;   // 32 blocks cover 32*TF2 outputs
  int kb0 = blockIdx.y * 37;
  int kb1 = kb0 + 37 < KB_ ? kb0 + 37 : KB_;
  const float* p = partial + out4;
  float ax = 0.f, ay = 0.f, az = 0.f, aw = 0.f;
  for (int kb = kb0; kb < kb1; ++kb) {
    float4 v = *(const float4*)&p[(size_t)kb * (32 * TF2_)];
    ax += v.x; ay += v.y; az += v.z; aw += v.w;
  }
  atomicAdd(&t1[out4 + 0], ax);
  atomicAdd(&t1[out4 + 1], ay);
  atomicAdd(&t1[out4 + 2], az);
  atomicAdd(&t1[out4 + 3], aw);
}

// ---------------------------------------------------------------- small gemms / head
__global__ __launch_bounds__(256) void small_gemm(const float* __restrict__ A,
                                                  const float* __restrict__ W,
                                                  const float* __restrict__ bias,
                                                  float* __restrict__ C,
                                                  int N, int K) {
  int m = blockIdx.y;
  int n = blockIdx.x * 256 + threadIdx.x;
  if (n >= N) return;
  float acc = bias[n];
  const float* ar = A + (size_t)m * K;
  for (int k = 0; k < K; ++k) acc += ar[k] * W[(size_t)k * N + n];
  C[(size_t)m * N + n] = acc;
}

__global__ __launch_bounds__(256) void cat_kernel(const float* __restrict__ cur,
                                                  const float* __restrict__ tgt,
                                                  const float* __restrict__ f,
                                                  float* __restrict__ outp) {
  int idx = blockIdx.x * 256 + threadIdx.x;
  const int total = B_ * 516;
  if (idx >= total) return;
  int m = idx / 516, j = idx % 516;
  float v;
  if (j < 2) v = cur[m * 2 + j];
  else if (j < 4) v = tgt[m * 2 + j - 2];
  else v = f[m * 512 + j - 4];
  outp[idx] = v;
}

__global__ __launch_bounds__(64) void head2_kernel(const float* __restrict__ h1,
                                                   const float* __restrict__ W,
                                                   const float* __restrict__ bias,
                                                   float* __restrict__ outp) {
  int m = blockIdx.x;
  int n = threadIdx.x;
  if (n < 4) {
    float acc = bias[n];
    for (int kk = 0; kk < TF_; ++kk) acc += h1[m * TF_ + kk] * W[kk * 4 + n];
    outp[m * 4 + n] = acc;
  }
}

// ---------------------------------------------------------------- launch
extern "C" void kernel_launch(void* const* d_in, const int* in_sizes, int n_in,
                              void* d_out, int out_size, void* d_ws, size_t ws_size,
                              hipStream_t stream) {
  const float* fov    = (const float*)d_in[0];
  const float* cur    = (const float*)d_in[1];
  const float* tgt    = (const float*)d_in[2];
  const float* conv_w = (const float*)d_in[3];
  const float* conv_b = (const float*)d_in[4];
  const float* ln_in_g = (const float*)d_in[5];
  const float* ln_in_b = (const float*)d_in[6];
  const float* blk_q  = (const float*)d_in[7];
  const float* blk_k  = (const float*)d_in[8];
  const float* blk_v  = (const float*)d_in[9];
  const float* ln1_g  = (const float*)d_in[10];
  const float* ln1_b  = (const float*)d_in[11];
  const float* w1     = (const float*)d_in[12];
  const float* b1     = (const float*)d_in[13];
  const float* ln2_g  = (const float*)d_in[14];
  const float* ln2_b  = (const float*)d_in[15];
  const float* w2     = (const float*)d_in[16];
  const float* b2     = (const float*)d_in[17];
  const float* ln3_g  = (const float*)d_in[18];
  const float* ln3_b  = (const float*)d_in[19];
  const float* img_g  = (const float*)d_in[20];
  const float* img_b  = (const float*)d_in[21];
  const float* t1w    = (const float*)d_in[22];
  const float* t1b    = (const float*)d_in[23];
  const float* tln1_g = (const float*)d_in[24];
  const float* tln1_b = (const float*)d_in[25];
  const float* t2w    = (const float*)d_in[26];
  const float* t2b    = (const float*)d_in[27];
  const float* tln2_g = (const float*)d_in[28];
  const float* tln2_b = (const float*)d_in[29];
  const float* h1w    = (const float*)d_in[30];
  const float* h1b    = (const float*)d_in[31];
  const float* hln_g  = (const float*)d_in[32];
  const float* hln_b  = (const float*)d_in[33];
  const float* h2w    = (const float*)d_in[34];
  const float* h2b    = (const float*)d_in[35];
  float* out = (float*)d_out;

  float* ws = (float*)d_ws;
  size_t off = 0;
  const size_t XE = (size_t)B_ * T_ * E_;      // 4,816,896
  const size_t XF = (size_t)B_ * T_ * FF_;     // 19,267,584
  float* x    = ws + off; off += XE;                   // residual (fp32)
  float* tmp  = ws + off; off += XE;                   // f (ln_big out)
  unsigned short* xn_b = (unsigned short*)(ws + off); off += XE / 2;   // LN out bf16 / patches
  unsigned short* hb_b = (unsigned short*)(ws + off); off += XF / 2;   // W1 out / ln2 bf16 (in-place)
  unsigned short* tmp_b = (unsigned short*)(ws + off); off += XE / 2;  // W2 out bf16
  unsigned short* qkv_bf = (unsigned short*)(ws + off); off += (size_t)B_ * T_ * QKV_LD / 2;
  unsigned short* cwb  = (unsigned short*)(ws + off); off += (size_t)E_ * E_ / 2;
  unsigned short* wqkvb = (unsigned short*)(ws + off); off += (size_t)NB_ * QKV_LD * E_ / 2;
  unsigned short* w1b  = (unsigned short*)(ws + off); off += (size_t)NB_ * E_ * FF_ / 2;
  unsigned short* w2b  = (unsigned short*)(ws + off); off += (size_t)NB_ * E_ * FF_ / 2;
  float* stats1 = ws + off; off += (size_t)B_ * T_ * 2;   // W1 row sums
  float* stats2 = ws + off; off += (size_t)B_ * T_ * 2;   // W2 row sums
  float* tpart = ws + off; off += (size_t)KB_ * 32 * TF2_;  // trunk1 partials (38.5 MB)
  float* t1 = ws + off; off += B_ * TF2_;
  float* t2 = ws + off; off += B_ * TF_;
  float* cb = ws + off; off += B_ * 516;
  float* h1 = ws + off; off += B_ * TF_;
  (void)ws_size; (void)in_sizes; (void)n_in; (void)out_size;

  const int M = B_ * T_;  // 6272
  dim3 blk(256);

  // ---- weight conversion (bf16, transposed to [N][K]) ----
  cvt_bf16<<<(E_ * E_ + 255) / 256, blk, 0, stream>>>(conv_w, cwb, E_ * E_);
  transpose_cvt<<<dim3(24, 24, NB_), blk, 0, stream>>>(blk_q, wqkvb + 0 * E_ * E_,
                                                       E_, E_, (long)E_ * E_, (long)QKV_LD * E_);
  transpose_cvt<<<dim3(24, 24, NB_), blk, 0, stream>>>(blk_k, wqkvb + 1 * E_ * E_,
                                                       E_, E_, (long)E_ * E_, (long)QKV_LD * E_);
  transpose_cvt<<<dim3(24, 24, NB_), blk, 0, stream>>>(blk_v, wqkvb + 2 * E_ * E_,
                                                       E_, E_, (long)E_ * E_, (long)QKV_LD * E_);
  transpose_cvt<<<dim3(96, 24, NB_), blk, 0, stream>>>(w1, w1b, E_, FF_,
                                                       (long)E_ * FF_, (long)E_ * FF_);
  transpose_cvt<<<dim3(24, 96, NB_), blk, 0, stream>>>(w2, w2b, FF_, E_,
                                                       (long)E_ * FF_, (long)E_ * FF_);

  // ---- patch embed ----
  gather_patches<<<(B_ * T_ * E_ + 255) / 256, blk, 0, stream>>>(fov, xn_b);
  gemm_bt_mfma<float><<<dim3(E_ / 128, M / 128), blk, 0, stream>>>(xn_b, cwb, conv_b, x,
                                                                   M, E_, E_, nullptr);

  // ---- block 0 ln_in (later blocks get it fused into ln3_fuse) ----
  ln_kernel<3><<<M, blk, 0, stream>>>(x, ln_in_g, ln_in_b,
                                      nullptr, nullptr, xn_b, 0, nullptr);

  // ---- transformer blocks ----
  for (int i = 0; i < NB_; ++i) {
    gemm_bt_mfma<unsigned short><<<dim3(QKV_LD / 128, M / 128), blk, 0, stream>>>(
        xn_b, wqkvb + (size_t)i * QKV_LD * E_, nullptr, qkv_bf, M, QKV_LD, E_, nullptr);
    attention_mfma<<<dim3(4, NH_, B_), blk, 0, stream>>>(qkv_bf, x);
    ln_kernel<3><<<M, blk, 0, stream>>>(x, ln1_g + i * E_, ln1_b + i * E_,
                                        nullptr, nullptr, xn_b, 0, stats1);
    gemm_bt_mfma<unsigned short><<<dim3(FF_ / 128, M / 128), blk, 0, stream>>>(
        xn_b, w1b + (size_t)i * E_ * FF_, b1 + i * FF_, hb_b, M, FF_, E_, stats1);
    ln2_fused<<<M, blk, 0, stream>>>(hb_b, stats1, ln2_g + i * FF_, ln2_b + i * FF_, stats2);
    gemm_bt_mfma<unsigned short><<<dim3(E_ / 128, M / 128), blk, 0, stream>>>(
        hb_b, w2b + (size_t)i * E_ * FF_, b2 + i * E_, tmp_b, M, E_, FF_, stats2);
    const float* gin = (i < NB_ - 1) ? ln_in_g + (i + 1) * E_ : nullptr;
    const float* bin = (i < NB_ - 1) ? ln_in_b + (i + 1) * E_ : nullptr;
    ln3_fuse<<<M, blk, 0, stream>>>(tmp_b, stats2, ln3_g + i * E_, ln3_b + i * E_,
                                    x, gin, bin, xn_b);
  }

  // ---- head ----
  float* f = tmp;
  ln_big<<<B_, dim3(1024), 0, stream>>>(x, img_g, img_b, f);
  init_bias_kernel<<<(B_ * TF2_ + 255) / 256, blk, 0, stream>>>(t1b, t1, B_, TF2_);
  trunk1_kernel<<<dim3(TF2_ / 256, KB_), blk, 0, stream>>>(f, t1w, tpart);
  trunk1_reduce<<<dim3(32, 8), blk, 0, stream>>>(tpart, t1);
  ln_kernel<4><<<B_, blk, 0, stream>>>(t1, tln1_g, tln1_b, nullptr, t1, nullptr, 1, nullptr);
  small_gemm<<<dim3(2, B_), blk, 0, stream>>>(t1, t2w, t2b, t2, TF_, TF2_);
  ln_kernel<2><<<B_, blk, 0, stream>>>(t2, tln2_g, tln2_b, nullptr, t2, nullptr, 1, nullptr);
  cat_kernel<<<(B_ * 516 + 255) / 256, blk, 0, stream>>>(cur, tgt, t2, cb);
  small_gemm<<<dim3(2, B_), blk, 0, stream>>>(cb, h1w, h1b, h1, TF_, 516);
  ln_kernel<2><<<B_, blk, 0, stream>>>(h1, hln_g, hln_b, nullptr, h1, nullptr, 1, nullptr);
  head2_kernel<<<B_, dim3(64), 0, stream>>>(h1, h2w, h2b, out);
}

// Round 5
// 3996.560 us; speedup vs baseline: 1.0646x; 1.0039x over previous
//
#include <hip/hip_runtime.h>
#include <math.h>

// TransformerPolicy forward — bf16 MFMA GEMMs + MFMA flash attention.
// B=32, T=196, E=768, NH=12, dh=64, NB=8, FF=3072, FLAT=150528, TF=512, NA=4
// R1 (verified, 4255 µs): fused LN-stats in GEMM epilogues, ln2 in-place bf16,
//     ln3+next-ln_in fused.
// R4 (verified, 4012 µs): trunk1 split-K partials (no 294-way atomics) + 8-deep
//     W-load batches at launch_bounds(256,2).
// R5: gemm_bt_mfma K-loop 1-phase -> 2-phase double-buffered LDS (T3 minimum):
//     prefetch tile t+1 via global_load_lds BEFORE compute of tile t; single
//     vmcnt(0)+barrier per k-step (was 2 barriers + mid-loop drain = fully
//     serial HBM latency every step).

#define B_    32
#define T_    196
#define E_    768
#define NH_   12
#define DH_   64
#define FF_   3072
#define NB_   8
#define FLAT_ 150528
#define TF2_  1024
#define TF_   512
#define QKV_LD 2304   // packed q|k|v output row stride

typedef __attribute__((ext_vector_type(8))) short short8;
typedef __attribute__((ext_vector_type(4))) float float4v;

static __device__ __forceinline__ unsigned short f2bf(float f) {
  unsigned int u = __float_as_uint(f);
  u = u + 0x7fffu + ((u >> 16) & 1u);   // round-to-nearest-even
  return (unsigned short)(u >> 16);
}

static __device__ __forceinline__ float bf2f(unsigned short u) {
  return __uint_as_float((unsigned int)u << 16);
}

// ---------------------------------------------------------------- patches (bf16 out)
__global__ __launch_bounds__(256) void gather_patches(const float* __restrict__ fov,
                                                      unsigned short* __restrict__ P) {
  int idx = blockIdx.x * 256 + threadIdx.x;
  const int total = B_ * T_ * E_;
  if (idx >= total) return;
  int m = idx / E_;
  int k = idx % E_;
  int b = m / T_, t = m % T_;
  int ph = t / 14, pw = t % 14;
  int c = k >> 8;
  int kh = (k >> 4) & 15;
  int kw = k & 15;
  P[idx] = f2bf(fov[((b * 3 + c) * 224 + ph * 16 + kh) * 224 + pw * 16 + kw]);
}

// elementwise fp32 -> bf16
__global__ __launch_bounds__(256) void cvt_bf16(const float* __restrict__ in,
                                                unsigned short* __restrict__ outp, int n) {
  int idx = blockIdx.x * 256 + threadIdx.x;
  if (idx < n) outp[idx] = f2bf(in[idx]);
}

// transpose + convert: in [R][C] fp32 (possibly NB matrices), out [C][R] bf16
__global__ __launch_bounds__(256) void transpose_cvt(const float* __restrict__ in,
                                                     unsigned short* __restrict__ outp,
                                                     int R, int Cc,
                                                     long in_ms, long out_ms) {
  __shared__ float tile[32][33];
  const float* ip = in + (size_t)blockIdx.z * in_ms;
  unsigned short* op = outp + (size_t)blockIdx.z * out_ms;
  int c0 = blockIdx.x * 32, r0 = blockIdx.y * 32;
  int tx = threadIdx.x & 31, ty = threadIdx.x >> 5;  // ty 0..7
#pragma unroll
  for (int i = 0; i < 32; i += 8)
    tile[ty + i][tx] = ip[(size_t)(r0 + ty + i) * Cc + c0 + tx];
  __syncthreads();
#pragma unroll
  for (int i = 0; i < 32; i += 8)
    op[(size_t)(c0 + ty + i) * R + r0 + tx] = f2bf(tile[tx][ty + i]);
}

// ---------------------------------------------------------------- MFMA GEMM
// C[M,N] = A[M,K](bf16) @ Bt[N,K](bf16)^T + bias. 128x128 tile, BK=32, 256 thr.
// 2-phase double-buffered LDS: prefetch k-tile t+1 while computing t.
// Optional: stats != nullptr -> atomically accumulate per-row (sum, sumsq) of the
// fp32 (pre-bf16-rounding) outputs into stats[2*row], stats[2*row+1].
template <typename OutT>
__global__ __launch_bounds__(256) void gemm_bt_mfma(const unsigned short* __restrict__ A,
                                                    const unsigned short* __restrict__ Bt,
                                                    const float* __restrict__ bias,
                                                    OutT* __restrict__ C,
                                                    int M, int N, int K,
                                                    float* __restrict__ stats) {
  __shared__ unsigned short As[2][128 * 32];  // [buf][row][k] row-major, 64B rows
  __shared__ unsigned short Bs[2][128 * 32];
  const int tid = threadIdx.x;
  const int wave = tid >> 6, lane = tid & 63;
  const int wr = wave >> 1, wc = wave & 1;
  const int m0 = blockIdx.y * 128, n0 = blockIdx.x * 128;

  float4v acc[4][4];
#pragma unroll
  for (int i = 0; i < 4; ++i)
#pragma unroll
    for (int j = 0; j < 4; ++j) acc[i][j] = (float4v){0.f, 0.f, 0.f, 0.f};

  const int sA = wave * 128 + lane;
  const int arow = sA >> 2;
  const int acol = (sA & 3) * 8;
  const unsigned short* Abase = A + (size_t)(m0 + arow) * K + acol;
  const unsigned short* Bbase = Bt + (size_t)(n0 + arow) * K + acol;

  const int kg = (lane >> 4) * 8;
  const int rsel = lane & 15;

  // stage k-tile kk into buffer buf (wave-uniform LDS dest + lane offset)
  auto STAGE = [&](int buf, int kk) {
    unsigned short* dA = &As[buf][0] + wave * 1024;
    unsigned short* dB = &Bs[buf][0] + wave * 1024;
    __builtin_amdgcn_global_load_lds(
        (const __attribute__((address_space(1))) unsigned int*)(const void*)(Abase + kk),
        (__attribute__((address_space(3))) unsigned int*)(void*)(dA), 16, 0, 0);
    __builtin_amdgcn_global_load_lds(
        (const __attribute__((address_space(1))) unsigned int*)(const void*)(Abase + (size_t)16 * K + kk),
        (__attribute__((address_space(3))) unsigned int*)(void*)(dA + 512), 16, 0, 0);
    __builtin_amdgcn_global_load_lds(
        (const __attribute__((address_space(1))) unsigned int*)(const void*)(Bbase + kk),
        (__attribute__((address_space(3))) unsigned int*)(void*)(dB), 16, 0, 0);
    __builtin_amdgcn_global_load_lds(
        (const __attribute__((address_space(1))) unsigned int*)(const void*)(Bbase + (size_t)16 * K + kk),
        (__attribute__((address_space(3))) unsigned int*)(void*)(dB + 512), 16, 0, 0);
  };

  STAGE(0, 0);
  asm volatile("s_waitcnt vmcnt(0)" ::: "memory");
  __syncthreads();

  int cur = 0;
  for (int k0 = 0; k0 < K; k0 += 32) {
    if (k0 + 32 < K) STAGE(cur ^ 1, k0 + 32);   // prefetch next tile (other buffer)

    const unsigned short* Asrc = &As[cur][0];
    const unsigned short* Bsrc = &Bs[cur][0];
    short8 af[4], bf[4];
#pragma unroll
    for (int mi = 0; mi < 4; ++mi)
      af[mi] = *(const short8*)(Asrc + (size_t)(wr * 64 + mi * 16 + rsel) * 32 + kg);
#pragma unroll
    for (int ni = 0; ni < 4; ++ni)
      bf[ni] = *(const short8*)(Bsrc + (size_t)(wc * 64 + ni * 16 + rsel) * 32 + kg);
#pragma unroll
    for (int mi = 0; mi < 4; ++mi)
#pragma unroll
      for (int ni = 0; ni < 4; ++ni)
        acc[mi][ni] = __builtin_amdgcn_mfma_f32_16x16x32_bf16(af[mi], bf[ni], acc[mi][ni], 0, 0, 0);

    // drain this wave's prefetch, then barrier: next iter reads the other buffer
    // and overwrites this one (all waves past their ds_reads at the barrier).
    asm volatile("s_waitcnt vmcnt(0)" ::: "memory");
    __syncthreads();
    cur ^= 1;
  }

  // C/D layout: col = lane&15, row = (lane>>4)*4 + r
  const int cr0 = m0 + wr * 64 + (lane >> 4) * 4;
  const int cc0 = n0 + wc * 64 + (lane & 15);
  float bv[4];
#pragma unroll
  for (int ni = 0; ni < 4; ++ni) bv[ni] = bias ? bias[cc0 + ni * 16] : 0.f;
#pragma unroll
  for (int mi = 0; mi < 4; ++mi) {
#pragma unroll
    for (int r = 0; r < 4; ++r) {
      int row = cr0 + mi * 16 + r;
      float s = 0.f, s2 = 0.f;
#pragma unroll
      for (int ni = 0; ni < 4; ++ni) {
        float v = acc[mi][ni][r] + bv[ni];
        if constexpr (sizeof(OutT) == 2)
          C[(size_t)row * N + cc0 + ni * 16] = f2bf(v);
        else
          C[(size_t)row * N + cc0 + ni * 16] = v;
        s += v; s2 += v * v;
      }
      if (stats) {
        // reduce over the 16 lanes (rsel) sharing this row; quad stays intact
#pragma unroll
        for (int o = 1; o < 16; o <<= 1) {
          s += __shfl_xor(s, o);
          s2 += __shfl_xor(s2, o);
        }
        if ((lane & 15) == 0) {
          atomicAdd(&stats[2 * row], s);
          atomicAdd(&stats[2 * row + 1], s2);
        }
      }
    }
  }
}

// ---------------------------------------------------------------- LayerNorm (reg-cached)
// zstats: optional stats buffer to zero for the *next* stats-accumulating GEMM.
template <int CNT>
__global__ __launch_bounds__(256) void ln_kernel(const float* __restrict__ in,
                                                 const float* __restrict__ g,
                                                 const float* __restrict__ bta,
                                                 const float* __restrict__ add_src,
                                                 float* __restrict__ out32,
                                                 unsigned short* __restrict__ out16,
                                                 int relu,
                                                 float* __restrict__ zstats) {
  const int R = CNT * 256;
  int row = blockIdx.x;
  if (zstats && threadIdx.x == 0) { zstats[2 * row] = 0.f; zstats[2 * row + 1] = 0.f; }
  const float* xr = in + (size_t)row * R;
  float v[CNT];
  float s = 0.f, s2 = 0.f;
#pragma unroll
  for (int i = 0; i < CNT; ++i) {
    float t = xr[i * 256 + threadIdx.x];
    v[i] = t; s += t; s2 += t * t;
  }
#pragma unroll
  for (int o = 32; o > 0; o >>= 1) { s += __shfl_down(s, o); s2 += __shfl_down(s2, o); }
  __shared__ float rs_[4], rs2_[4];
  int wave = threadIdx.x >> 6, lane = threadIdx.x & 63;
  if (lane == 0) { rs_[wave] = s; rs2_[wave] = s2; }
  __syncthreads();
  s = rs_[0] + rs_[1] + rs_[2] + rs_[3];
  s2 = rs2_[0] + rs2_[1] + rs2_[2] + rs2_[3];
  float mean = s / (float)R;
  float inv = rsqrtf(s2 / (float)R - mean * mean + 1e-5f);
#pragma unroll
  for (int i = 0; i < CNT; ++i) {
    int c = i * 256 + threadIdx.x;
    float t = (v[i] - mean) * inv * g[c] + bta[c];
    if (relu) t = fmaxf(t, 0.f);
    if (add_src) t += add_src[(size_t)row * R + c];
    if (out32) out32[(size_t)row * R + c] = t;
    else out16[(size_t)row * R + c] = f2bf(t);
  }
}

// LN2+ReLU applied in-place on bf16 W1 output using precomputed row stats.
// Also zeroes stats2 for the following W2 GEMM.
__global__ __launch_bounds__(256) void ln2_fused(unsigned short* __restrict__ hb,
                                                 const float* __restrict__ stats,
                                                 const float* __restrict__ g,
                                                 const float* __restrict__ bta,
                                                 float* __restrict__ zstats) {
  int row = blockIdx.x;
  if (threadIdx.x == 0) { zstats[2 * row] = 0.f; zstats[2 * row + 1] = 0.f; }
  float s = stats[2 * row], s2 = stats[2 * row + 1];
  const float R = (float)FF_;
  float mean = s / R;
  float inv = rsqrtf(s2 / R - mean * mean + 1e-5f);
  unsigned short* hr = hb + (size_t)row * FF_;
#pragma unroll
  for (int i = 0; i < 6; ++i) {
    int c = (i * 256 + threadIdx.x) * 2;
    unsigned int u = *(const unsigned int*)(hr + c);
    float2 gv = *(const float2*)(g + c);
    float2 bv = *(const float2*)(bta + c);
    float v0 = __uint_as_float((u & 0xffffu) << 16);
    float v1 = __uint_as_float(u & 0xffff0000u);
    float t0 = fmaxf((v0 - mean) * inv * gv.x + bv.x, 0.f);
    float t1 = fmaxf((v1 - mean) * inv * gv.y + bv.y, 0.f);
    *(unsigned int*)(hr + c) = (unsigned int)f2bf(t0) | ((unsigned int)f2bf(t1) << 16);
  }
}

// x += LN3(h2) using precomputed stats; then (optionally) compute next block's
// ln_in over the updated row (full row is live in registers) -> xn bf16.
__global__ __launch_bounds__(256) void ln3_fuse(const unsigned short* __restrict__ h2,
                                                const float* __restrict__ stats,
                                                const float* __restrict__ g3,
                                                const float* __restrict__ b3,
                                                float* __restrict__ x,
                                                const float* __restrict__ gin,
                                                const float* __restrict__ bin,
                                                unsigned short* __restrict__ xn) {
  int row = blockIdx.x;
  float s = stats[2 * row], s2 = stats[2 * row + 1];
  const float R = (float)E_;
  float mean = s / R;
  float inv = rsqrtf(s2 / R - mean * mean + 1e-5f);
  const unsigned short* hr = h2 + (size_t)row * E_;
  float* xr = x + (size_t)row * E_;
  float y[3];
  float ys = 0.f, ys2 = 0.f;
#pragma unroll
  for (int i = 0; i < 3; ++i) {
    int c = i * 256 + threadIdx.x;
    float hv = bf2f(hr[c]);
    float t = (hv - mean) * inv * g3[c] + b3[c];
    float yy = xr[c] + t;
    xr[c] = yy;
    y[i] = yy; ys += yy; ys2 += yy * yy;
  }
  if (!gin) return;  // last block: no following ln_in
#pragma unroll
  for (int o = 32; o > 0; o >>= 1) { ys += __shfl_down(ys, o); ys2 += __shfl_down(ys2, o); }
  __shared__ float rs_[4], rs2_[4];
  int wave = threadIdx.x >> 6, lane = threadIdx.x & 63;
  if (lane == 0) { rs_[wave] = ys; rs2_[wave] = ys2; }
  __syncthreads();
  ys = rs_[0] + rs_[1] + rs_[2] + rs_[3];
  ys2 = rs2_[0] + rs2_[1] + rs2_[2] + rs2_[3];
  float m2 = ys / R;
  float inv2 = rsqrtf(ys2 / R - m2 * m2 + 1e-5f);
#pragma unroll
  for (int i = 0; i < 3; ++i) {
    int c = i * 256 + threadIdx.x;
    xn[(size_t)row * E_ + c] = f2bf((y[i] - m2) * inv2 * gin[c] + bin[c]);
  }
}

// LN over FLAT per sample (32 rows)
__global__ __launch_bounds__(1024) void ln_big(const float* __restrict__ in,
                                               const float* __restrict__ g,
                                               const float* __restrict__ bta,
                                               float* __restrict__ outp) {
  __shared__ float red[16], red2[16];
  int row = blockIdx.x;
  const float* xr = in + (size_t)row * FLAT_;
  float s = 0.f, s2 = 0.f;
  for (int i = threadIdx.x; i < FLAT_; i += 1024) { float t = xr[i]; s += t; s2 += t * t; }
  for (int o = 32; o > 0; o >>= 1) { s += __shfl_down(s, o); s2 += __shfl_down(s2, o); }
  int wave = threadIdx.x >> 6, lane = threadIdx.x & 63;
  if (lane == 0) { red[wave] = s; red2[wave] = s2; }
  __syncthreads();
  if (threadIdx.x == 0) {
    float a = 0.f, b2 = 0.f;
    for (int i = 0; i < 16; ++i) { a += red[i]; b2 += red2[i]; }
    red[0] = a; red2[0] = b2;
  }
  __syncthreads();
  s = red[0]; s2 = red2[0];
  float mean = s / (float)FLAT_;
  float inv = rsqrtf(s2 / (float)FLAT_ - mean * mean + 1e-5f);
  for (int i = threadIdx.x; i < FLAT_; i += 1024)
    outp[(size_t)row * FLAT_ + i] = (xr[i] - mean) * inv * g[i] + bta[i];
}

// ---------------------------------------------------------------- attention (MFMA flash)
// qkv bf16 [B*T][2304]: q@0, k@+768, v@+1536. x[b,t,h*64+d] += softmax(qk^T/14) v.
__global__ __launch_bounds__(256) void attention_mfma(const unsigned short* __restrict__ qkv,
                                                      float* __restrict__ x) {
  __shared__ unsigned short smem[28672];     // 57,344 B
  unsigned short* Kh = smem;                 // [2 half][224 s][32 k]
  unsigned short* Vt = smem + 14336;         // [7 chunk][64 d][32 s]
  unsigned short* Ps = smem;                 // [4 wave][7 chunk][16 m][32 k] (aliases Kh)
  const int chunk = blockIdx.x, h = blockIdx.y, b = blockIdx.z;
  const int tid = threadIdx.x, wave = tid >> 6, lane = tid & 63;
  const int quad = lane >> 4, rsel = lane & 15;

  // ---- stage K (row-major halves) and V (transposed [d][s]) ----
  for (int task = tid; task < 1792; task += 256) {
    int s = task >> 3, seg = task & 7;       // seg: 8-col group
    short8 kv = {0, 0, 0, 0, 0, 0, 0, 0};
    short8 vv = {0, 0, 0, 0, 0, 0, 0, 0};
    if (s < 196) {
      const unsigned short* gp = qkv + (size_t)(b * 196 + s) * 2304 + h * 64 + seg * 8;
      kv = *(const short8*)(gp + 768);
      vv = *(const short8*)(gp + 1536);
    }
    *(short8*)(Kh + (seg >> 2) * 7168 + s * 32 + (seg & 3) * 8) = kv;
    int c = s >> 5, sw = s & 31;
#pragma unroll
    for (int j = 0; j < 8; ++j)
      Vt[c * 2048 + (seg * 8 + j) * 32 + sw] = (unsigned short)vv[j];
  }

  // Q A-frags direct from global (A[m=lane&15][k=quad*8+j]); clamp padded rows
  int qrow = chunk * 64 + wave * 16 + rsel;
  int qc = qrow < 196 ? qrow : 195;
  const unsigned short* qp = qkv + (size_t)(b * 196 + qc) * 2304 + h * 64 + quad * 8;
  short8 a0 = *(const short8*)qp;
  short8 a1 = *(const short8*)(qp + 32);

  __syncthreads();

  // ---- S = Q K^T ----
  float4v S[14];
#pragma unroll
  for (int ni = 0; ni < 14; ++ni) S[ni] = (float4v){0.f, 0.f, 0.f, 0.f};
#pragma unroll
  for (int ni = 0; ni < 14; ++ni) {
    const unsigned short* kb = Kh + (ni * 16 + rsel) * 32 + quad * 8;
    S[ni] = __builtin_amdgcn_mfma_f32_16x16x32_bf16(a0, *(const short8*)kb, S[ni], 0, 0, 0);
    S[ni] = __builtin_amdgcn_mfma_f32_16x16x32_bf16(a1, *(const short8*)(kb + 7168), S[ni], 0, 0, 0);
  }

  // ---- softmax (exact, per row t = quad*4 + r) ----
  const float scale = 1.0f / 14.0f;
  float mr[4] = {-1e30f, -1e30f, -1e30f, -1e30f};
#pragma unroll
  for (int ni = 0; ni < 14; ++ni) {
    int col = ni * 16 + rsel;
#pragma unroll
    for (int r = 0; r < 4; ++r) {
      float v = (col < 196) ? S[ni][r] * scale : -1e30f;
      S[ni][r] = v;
      mr[r] = fmaxf(mr[r], v);
    }
  }
#pragma unroll
  for (int o = 1; o < 16; o <<= 1) {
#pragma unroll
    for (int r = 0; r < 4; ++r) mr[r] = fmaxf(mr[r], __shfl_xor(mr[r], o));
  }
  float lr[4] = {0.f, 0.f, 0.f, 0.f};
#pragma unroll
  for (int ni = 0; ni < 14; ++ni) {
#pragma unroll
    for (int r = 0; r < 4; ++r) {
      float p = __expf(S[ni][r] - mr[r]);
      S[ni][r] = p;
      lr[r] += p;
    }
  }
#pragma unroll
  for (int o = 1; o < 16; o <<= 1) {
#pragma unroll
    for (int r = 0; r < 4; ++r) lr[r] += __shfl_xor(lr[r], o);
  }

  // ---- P (C-layout) -> LDS -> A-layout ----
  __syncthreads();  // all waves done reading Kh
#pragma unroll
  for (int ni = 0; ni < 14; ++ni) {
    int c = ni >> 1, cw = (ni & 1) * 16 + rsel;
#pragma unroll
    for (int r = 0; r < 4; ++r)
      Ps[wave * 3584 + c * 512 + (quad * 4 + r) * 32 + cw] = f2bf(S[ni][r]);
  }
  __syncthreads();

  // ---- O = P V ----
  float4v O[4];
#pragma unroll
  for (int nd = 0; nd < 4; ++nd) O[nd] = (float4v){0.f, 0.f, 0.f, 0.f};
#pragma unroll
  for (int c = 0; c < 7; ++c) {
    short8 pa = *(const short8*)(Ps + wave * 3584 + c * 512 + rsel * 32 + quad * 8);
#pragma unroll
    for (int nd = 0; nd < 4; ++nd) {
      short8 vb = *(const short8*)(Vt + c * 2048 + (nd * 16 + rsel) * 32 + quad * 8);
      O[nd] = __builtin_amdgcn_mfma_f32_16x16x32_bf16(pa, vb, O[nd], 0, 0, 0);
    }
  }

  // ---- x += O / l (disjoint (t,h) slices: race-free) ----
  int t0 = chunk * 64 + wave * 16 + quad * 4;
  float invl[4];
#pragma unroll
  for (int r = 0; r < 4; ++r) invl[r] = 1.0f / lr[r];
#pragma unroll
  for (int r = 0; r < 4; ++r) {
    int t = t0 + r;
    if (t < 196) {
      float* xp = x + (size_t)(b * 196 + t) * 768 + h * 64 + rsel;
#pragma unroll
      for (int nd = 0; nd < 4; ++nd) xp[nd * 16] += O[nd][r] * invl[r];
    }
  }
}

// ---------------------------------------------------------------- trunk1
__global__ __launch_bounds__(256) void init_bias_kernel(const float* __restrict__ bias,
                                                        float* __restrict__ outp,
                                                        int M, int N) {
  int idx = blockIdx.x * 256 + threadIdx.x;
  if (idx < M * N) outp[idx] = bias[idx % N];
}

#define TKS_ 512
#define KB_  (FLAT_ / TKS_)   // 294 k-blocks

// stage 1: partial[kb][32][TF2] = f[32][k-slice] @ W[k-slice][TF2]. No atomics.
__global__ __launch_bounds__(256, 2) void trunk1_kernel(const float* __restrict__ f,
                                                        const float* __restrict__ W,
                                                        float* __restrict__ partial) {
  __shared__ float fs[32][33];
  const int tid = threadIdx.x;
  const int nt = tid & 63;
  const int mg = tid >> 6;
  const int n = blockIdx.x * 256 + nt * 4;
  const int k0 = blockIdx.y * TKS_;
  float4 acc[8];
#pragma unroll
  for (int r = 0; r < 8; ++r) acc[r] = make_float4(0.f, 0.f, 0.f, 0.f);
  const int lm = tid >> 3;
  const int lk = (tid & 7) * 4;
  for (int kc = 0; kc < TKS_; kc += 32) {
    __syncthreads();
    *(float4*)&fs[lm][lk] = *(const float4*)&f[(size_t)lm * FLAT_ + k0 + kc + lk];
    __syncthreads();
#pragma unroll
    for (int kb8 = 0; kb8 < 32; kb8 += 8) {
      // batch-issue 8 independent float4 W loads (needs the 256-VGPR budget)
      float4 w[8];
#pragma unroll
      for (int j = 0; j < 8; ++j)
        w[j] = *(const float4*)&W[(size_t)(k0 + kc + kb8 + j) * TF2_ + n];
#pragma unroll
      for (int j = 0; j < 8; ++j) {
#pragma unroll
        for (int r = 0; r < 8; ++r) {
          float fv = fs[mg * 8 + r][kb8 + j];
          acc[r].x += fv * w[j].x; acc[r].y += fv * w[j].y;
          acc[r].z += fv * w[j].z; acc[r].w += fv * w[j].w;
        }
      }
    }
  }
  const size_t base = ((size_t)blockIdx.y * 32 + mg * 8) * TF2_ + n;
#pragma unroll
  for (int r = 0; r < 8; ++r)
    *(float4*)&partial[base + (size_t)r * TF2_] = acc[r];
}

// stage 2: t1 (bias-initialized) += sum_kb partial[kb]. grid (32, 8) split-K.
__global__ __launch_bounds__(256) void trunk1_reduce(const float* __restrict__ partial,
                                                     float* __restrict__ t1) {
  int out4 = blockIdx.x * 1024 + threadIdx.x * 4;   // 32 blocks cover 32*TF2 outputs
  int kb0 = blockIdx.y * 37;
  int kb1 = kb0 + 37 < KB_ ? kb0 + 37 : KB_;
  const float* p = partial + out4;
  float ax = 0.f, ay = 0.f, az = 0.f, aw = 0.f;
  for (int kb = kb0; kb < kb1; ++kb) {
    float4 v = *(const float4*)&p[(size_t)kb * (32 * TF2_)];
    ax += v.x; ay += v.y; az += v.z; aw += v.w;
  }
  atomicAdd(&t1[out4 + 0], ax);
  atomicAdd(&t1[out4 + 1], ay);
  atomicAdd(&t1[out4 + 2], az);
  atomicAdd(&t1[out4 + 3], aw);
}

// ---------------------------------------------------------------- small gemms / head
__global__ __launch_bounds__(256) void small_gemm(const float* __restrict__ A,
                                                  const float* __restrict__ W,
                                                  const float* __restrict__ bias,
                                                  float* __restrict__ C,
                                                  int N, int K) {
  int m = blockIdx.y;
  int n = blockIdx.x * 256 + threadIdx.x;
  if (n >= N) return;
  float acc = bias[n];
  const float* ar = A + (size_t)m * K;
  for (int k = 0; k < K; ++k) acc += ar[k] * W[(size_t)k * N + n];
  C[(size_t)m * N + n] = acc;
}

__global__ __launch_bounds__(256) void cat_kernel(const float* __restrict__ cur,
                                                  const float* __restrict__ tgt,
                                                  const float* __restrict__ f,
                                                  float* __restrict__ outp) {
  int idx = blockIdx.x * 256 + threadIdx.x;
  const int total = B_ * 516;
  if (idx >= total) return;
  int m = idx / 516, j = idx % 516;
  float v;
  if (j < 2) v = cur[m * 2 + j];
  else if (j < 4) v = tgt[m * 2 + j - 2];
  else v = f[m * 512 + j - 4];
  outp[idx] = v;
}

__global__ __launch_bounds__(64) void head2_kernel(const float* __restrict__ h1,
                                                   const float* __restrict__ W,
                                                   const float* __restrict__ bias,
                                                   float* __restrict__ outp) {
  int m = blockIdx.x;
  int n = threadIdx.x;
  if (n < 4) {
    float acc = bias[n];
    for (int kk = 0; kk < TF_; ++kk) acc += h1[m * TF_ + kk] * W[kk * 4 + n];
    outp[m * 4 + n] = acc;
  }
}

// ---------------------------------------------------------------- launch
extern "C" void kernel_launch(void* const* d_in, const int* in_sizes, int n_in,
                              void* d_out, int out_size, void* d_ws, size_t ws_size,
                              hipStream_t stream) {
  const float* fov    = (const float*)d_in[0];
  const float* cur    = (const float*)d_in[1];
  const float* tgt    = (const float*)d_in[2];
  const float* conv_w = (const float*)d_in[3];
  const float* conv_b = (const float*)d_in[4];
  const float* ln_in_g = (const float*)d_in[5];
  const float* ln_in_b = (const float*)d_in[6];
  const float* blk_q  = (const float*)d_in[7];
  const float* blk_k  = (const float*)d_in[8];
  const float* blk_v  = (const float*)d_in[9];
  const float* ln1_g  = (const float*)d_in[10];
  const float* ln1_b  = (const float*)d_in[11];
  const float* w1     = (const float*)d_in[12];
  const float* b1     = (const float*)d_in[13];
  const float* ln2_g  = (const float*)d_in[14];
  const float* ln2_b  = (const float*)d_in[15];
  const float* w2     = (const float*)d_in[16];
  const float* b2     = (const float*)d_in[17];
  const float* ln3_g  = (const float*)d_in[18];
  const float* ln3_b  = (const float*)d_in[19];
  const float* img_g  = (const float*)d_in[20];
  const float* img_b  = (const float*)d_in[21];
  const float* t1w    = (const float*)d_in[22];
  const float* t1b    = (const float*)d_in[23];
  const float* tln1_g = (const float*)d_in[24];
  const float* tln1_b = (const float*)d_in[25];
  const float* t2w    = (const float*)d_in[26];
  const float* t2b    = (const float*)d_in[27];
  const float* tln2_g = (const float*)d_in[28];
  const float* tln2_b = (const float*)d_in[29];
  const float* h1w    = (const float*)d_in[30];
  const float* h1b    = (const float*)d_in[31];
  const float* hln_g  = (const float*)d_in[32];
  const float* hln_b  = (const float*)d_in[33];
  const float* h2w    = (const float*)d_in[34];
  const float* h2b    = (const float*)d_in[35];
  float* out = (float*)d_out;

  float* ws = (float*)d_ws;
  size_t off = 0;
  const size_t XE = (size_t)B_ * T_ * E_;      // 4,816,896
  const size_t XF = (size_t)B_ * T_ * FF_;     // 19,267,584
  float* x    = ws + off; off += XE;                   // residual (fp32)
  float* tmp  = ws + off; off += XE;                   // f (ln_big out)
  unsigned short* xn_b = (unsigned short*)(ws + off); off += XE / 2;   // LN out bf16 / patches
  unsigned short* hb_b = (unsigned short*)(ws + off); off += XF / 2;   // W1 out / ln2 bf16 (in-place)
  unsigned short* tmp_b = (unsigned short*)(ws + off); off += XE / 2;  // W2 out bf16
  unsigned short* qkv_bf = (unsigned short*)(ws + off); off += (size_t)B_ * T_ * QKV_LD / 2;
  unsigned short* cwb  = (unsigned short*)(ws + off); off += (size_t)E_ * E_ / 2;
  unsigned short* wqkvb = (unsigned short*)(ws + off); off += (size_t)NB_ * QKV_LD * E_ / 2;
  unsigned short* w1b  = (unsigned short*)(ws + off); off += (size_t)NB_ * E_ * FF_ / 2;
  unsigned short* w2b  = (unsigned short*)(ws + off); off += (size_t)NB_ * E_ * FF_ / 2;
  float* stats1 = ws + off; off += (size_t)B_ * T_ * 2;   // W1 row sums
  float* stats2 = ws + off; off += (size_t)B_ * T_ * 2;   // W2 row sums
  float* tpart = ws + off; off += (size_t)KB_ * 32 * TF2_;  // trunk1 partials (38.5 MB)
  float* t1 = ws + off; off += B_ * TF2_;
  float* t2 = ws + off; off += B_ * TF_;
  float* cb = ws + off; off += B_ * 516;
  float* h1 = ws + off; off += B_ * TF_;
  (void)ws_size; (void)in_sizes; (void)n_in; (void)out_size;

  const int M = B_ * T_;  // 6272
  dim3 blk(256);

  // ---- weight conversion (bf16, transposed to [N][K]) ----
  cvt_bf16<<<(E_ * E_ + 255) / 256, blk, 0, stream>>>(conv_w, cwb, E_ * E_);
  transpose_cvt<<<dim3(24, 24, NB_), blk, 0, stream>>>(blk_q, wqkvb + 0 * E_ * E_,
                                                       E_, E_, (long)E_ * E_, (long)QKV_LD * E_);
  transpose_cvt<<<dim3(24, 24, NB_), blk, 0, stream>>>(blk_k, wqkvb + 1 * E_ * E_,
                                                       E_, E_, (long)E_ * E_, (long)QKV_LD * E_);
  transpose_cvt<<<dim3(24, 24, NB_), blk, 0, stream>>>(blk_v, wqkvb + 2 * E_ * E_,
                                                       E_, E_, (long)E_ * E_, (long)QKV_LD * E_);
  transpose_cvt<<<dim3(96, 24, NB_), blk, 0, stream>>>(w1, w1b, E_, FF_,
                                                       (long)E_ * FF_, (long)E_ * FF_);
  transpose_cvt<<<dim3(24, 96, NB_), blk, 0, stream>>>(w2, w2b, FF_, E_,
                                                       (long)E_ * FF_, (long)E_ * FF_);

  // ---- patch embed ----
  gather_patches<<<(B_ * T_ * E_ + 255) / 256, blk, 0, stream>>>(fov, xn_b);
  gemm_bt_mfma<float><<<dim3(E_ / 128, M / 128), blk, 0, stream>>>(xn_b, cwb, conv_b, x,
                                                                   M, E_, E_, nullptr);

  // ---- block 0 ln_in (later blocks get it fused into ln3_fuse) ----
  ln_kernel<3><<<M, blk, 0, stream>>>(x, ln_in_g, ln_in_b,
                                      nullptr, nullptr, xn_b, 0, nullptr);

  // ---- transformer blocks ----
  for (int i = 0; i < NB_; ++i) {
    gemm_bt_mfma<unsigned short><<<dim3(QKV_LD / 128, M / 128), blk, 0, stream>>>(
        xn_b, wqkvb + (size_t)i * QKV_LD * E_, nullptr, qkv_bf, M, QKV_LD, E_, nullptr);
    attention_mfma<<<dim3(4, NH_, B_), blk, 0, stream>>>(qkv_bf, x);
    ln_kernel<3><<<M, blk, 0, stream>>>(x, ln1_g + i * E_, ln1_b + i * E_,
                                        nullptr, nullptr, xn_b, 0, stats1);
    gemm_bt_mfma<unsigned short><<<dim3(FF_ / 128, M / 128), blk, 0, stream>>>(
        xn_b, w1b + (size_t)i * E_ * FF_, b1 + i * FF_, hb_b, M, FF_, E_, stats1);
    ln2_fused<<<M, blk, 0, stream>>>(hb_b, stats1, ln2_g + i * FF_, ln2_b + i * FF_, stats2);
    gemm_bt_mfma<unsigned short><<<dim3(E_ / 128, M / 128), blk, 0, stream>>>(
        hb_b, w2b + (size_t)i * E_ * FF_, b2 + i * E_, tmp_b, M, E_, FF_, stats2);
    const float* gin = (i < NB_ - 1) ? ln_in_g + (i + 1) * E_ : nullptr;
    const float* bin = (i < NB_ - 1) ? ln_in_b + (i + 1) * E_ : nullptr;
    ln3_fuse<<<M, blk, 0, stream>>>(tmp_b, stats2, ln3_g + i * E_, ln3_b + i * E_,
                                    x, gin, bin, xn_b);
  }

  // ---- head ----
  float* f = tmp;
  ln_big<<<B_, dim3(1024), 0, stream>>>(x, img_g, img_b, f);
  init_bias_kernel<<<(B_ * TF2_ + 255) / 256, blk, 0, stream>>>(t1b, t1, B_, TF2_);
  trunk1_kernel<<<dim3(TF2_ / 256, KB_), blk, 0, stream>>>(f, t1w, tpart);
  trunk1_reduce<<<dim3(32, 8), blk, 0, stream>>>(tpart, t1);
  ln_kernel<4><<<B_, blk, 0, stream>>>(t1, tln1_g, tln1_b, nullptr, t1, nullptr, 1, nullptr);
  small_gemm<<<dim3(2, B_), blk, 0, stream>>>(t1, t2w, t2b, t2, TF_, TF2_);
  ln_kernel<2><<<B_, blk, 0, stream>>>(t2, tln2_g, tln2_b, nullptr, t2, nullptr, 1, nullptr);
  cat_kernel<<<(B_ * 516 + 255) / 256, blk, 0, stream>>>(cur, tgt, t2, cb);
  small_gemm<<<dim3(2, B_), blk, 0, stream>>>(cb, h1w, h1b, h1, TF_, 516);
  ln_kernel<2><<<B_, blk, 0, stream>>>(h1, hln_g, hln_b, nullptr, h1, nullptr, 1, nullptr);
  head2_kernel<<<B_, dim3(64), 0, stream>>>(h1, h2w, h2b, out);
}